// Round 1
// baseline (4076.827 us; speedup 1.0000x reference)
//
#include <hip/hip_runtime.h>
#include <math.h>

// ---------------- problem constants ----------------
// B=8, N=2048, F=64, H=256, LAT=64, K1=1024, K2=512
#define BATCH 8

// ---------------- generic tiled GEMM ----------------
// C[b] = act( op(A)[b] @ B[b] + bias )
// op(A) = A (TRANSA=0, phys [M,K], lda=K)  or  A^T (TRANSA=1, phys [K,M], lda=M)
// B phys [K,N], ldb=N.  C [M,N], ldc=N.  Batch via element strides (0 = shared).
// Requires: M%64==0, N%64==0, K%16==0.

#define TILE 64
#define KT 16

template <int ACT>
__device__ __forceinline__ float act_apply(float x) {
  if (ACT == 1) return fmaxf(x, 0.0f);
  if (ACT == 2) return (x > 20.0f) ? x : log1pf(expf(x));
  return x;
}

template <int TRANSA, int ACT, bool HAS_BIAS>
__global__ __launch_bounds__(256) void gemm_k(
    const float* __restrict__ A, const float* __restrict__ Bm,
    const float* __restrict__ bias, float* __restrict__ C,
    int M, int N, int K, long long sA, long long sB, long long sC) {
  __shared__ float As[KT][TILE + 4];
  __shared__ float Bs[KT][TILE + 4];

  const int b = blockIdx.z;
  A += (long long)b * sA;
  Bm += (long long)b * sB;
  C += (long long)b * sC;

  const int m0 = blockIdx.y * TILE;
  const int n0 = blockIdx.x * TILE;
  const int t = threadIdx.x;
  const int tn = (t % 16) * 4;
  const int tm = (t / 16) * 4;

  float acc[4][4] = {};

  for (int k0 = 0; k0 < K; k0 += KT) {
    // ---- load A tile into As[k][m] ----
    if (TRANSA == 0) {
      // A[m0+lm][k0+lk..lk+3], lda=K. float4 per thread.
      const int lm = t >> 2;          // 0..63
      const int lk = (t & 3) * 4;     // 0,4,8,12
      const float4 v = *(const float4*)(A + (long long)(m0 + lm) * K + (k0 + lk));
      As[lk + 0][lm] = v.x;
      As[lk + 1][lm] = v.y;
      As[lk + 2][lm] = v.z;
      As[lk + 3][lm] = v.w;
    } else {
      // A[k0+..][m0+lm], lda=M. coalesced rows.
      const int lk = t >> 6;          // 0..3
      const int lm = t & 63;
#pragma unroll
      for (int i = 0; i < 4; ++i)
        As[lk + i * 4][lm] = A[(long long)(k0 + lk + i * 4) * M + (m0 + lm)];
    }
    // ---- load B tile into Bs[k][n] ----
    {
      const int lk = t >> 6;
      const int ln = t & 63;
#pragma unroll
      for (int i = 0; i < 4; ++i)
        Bs[lk + i * 4][ln] = Bm[(long long)(k0 + lk + i * 4) * N + (n0 + ln)];
    }
    __syncthreads();

#pragma unroll
    for (int kk = 0; kk < KT; ++kk) {
      const float4 av = *(const float4*)&As[kk][tm];
      const float4 bv = *(const float4*)&Bs[kk][tn];
      const float a[4] = {av.x, av.y, av.z, av.w};
      const float bb[4] = {bv.x, bv.y, bv.z, bv.w};
#pragma unroll
      for (int i = 0; i < 4; ++i)
#pragma unroll
        for (int j = 0; j < 4; ++j) acc[i][j] += a[i] * bb[j];
    }
    __syncthreads();
  }

  // ---- epilogue ----
#pragma unroll
  for (int i = 0; i < 4; ++i) {
    const long long m = m0 + tm + i;
#pragma unroll
    for (int j = 0; j < 4; ++j) {
      const int n = n0 + tn + j;
      float v = acc[i][j];
      if (HAS_BIAS) v += bias[n];
      C[m * N + n] = act_apply<ACT>(v);
    }
  }
}

// ---------------- row softmax (in place) ----------------
__global__ __launch_bounds__(256) void softmax_rows_k(float* __restrict__ x, int L) {
  const long long row = blockIdx.x;
  float* p = x + row * (long long)L;
  const int t = threadIdx.x;
  __shared__ float red[256];

  float mx = -INFINITY;
  for (int i = t; i < L; i += 256) mx = fmaxf(mx, p[i]);
  red[t] = mx;
  __syncthreads();
  for (int s = 128; s > 0; s >>= 1) {
    if (t < s) red[t] = fmaxf(red[t], red[t + s]);
    __syncthreads();
  }
  mx = red[0];
  __syncthreads();

  float sum = 0.0f;
  for (int i = t; i < L; i += 256) {
    const float e = expf(p[i] - mx);
    p[i] = e;
    sum += e;
  }
  red[t] = sum;
  __syncthreads();
  for (int s = 128; s > 0; s >>= 1) {
    if (t < s) red[t] += red[t + s];
    __syncthreads();
  }
  const float inv = 1.0f / red[0];
  for (int i = t; i < L; i += 256) p[i] *= inv;
}

// ---------------- reparameterize ----------------
// h3: [B,512,128] (mean | log_var). eps: [B,512,64].
__global__ __launch_bounds__(256) void reparam_k(
    const float* __restrict__ h3, const float* __restrict__ eps,
    float* __restrict__ out_mean, float* __restrict__ out_lv,
    float* __restrict__ zlat, int total) {
  const int i = blockIdx.x * 256 + threadIdx.x;
  if (i >= total) return;
  const int j = i & 63;
  const long long row = i >> 6;  // b*512+m
  const float mean = h3[row * 128 + j];
  const float lv = h3[row * 128 + 64 + j];
  out_mean[i] = mean;
  out_lv[i] = lv;
  zlat[i] = mean + expf(0.5f * lv) * eps[i];
}

// ---------------- host-side dispatch ----------------
static void gemm(hipStream_t st, const float* A, const float* Bm, const float* bias,
                 float* C, int M, int N, int K, long long sA, long long sB,
                 long long sC, int transA, int act) {
  dim3 g(N / TILE, M / TILE, BATCH), blk(256);
  if (transA) {
    gemm_k<1, 0, false><<<g, blk, 0, st>>>(A, Bm, nullptr, C, M, N, K, sA, sB, sC);
  } else if (bias) {
    if (act == 1)
      gemm_k<0, 1, true><<<g, blk, 0, st>>>(A, Bm, bias, C, M, N, K, sA, sB, sC);
    else if (act == 2)
      gemm_k<0, 2, true><<<g, blk, 0, st>>>(A, Bm, bias, C, M, N, K, sA, sB, sC);
    else
      gemm_k<0, 0, true><<<g, blk, 0, st>>>(A, Bm, bias, C, M, N, K, sA, sB, sC);
  } else {
    gemm_k<0, 0, false><<<g, blk, 0, st>>>(A, Bm, nullptr, C, M, N, K, sA, sB, sC);
  }
}

extern "C" void kernel_launch(void* const* d_in, const int* in_sizes, int n_in,
                              void* d_out, int out_size, void* d_ws, size_t ws_size,
                              hipStream_t stream) {
  const float* x     = (const float*)d_in[0];   // [8,2048,64]
  const float* eps   = (const float*)d_in[1];   // [8,512,64]
  const float* adj   = (const float*)d_in[2];   // [2048,2048]
  const float* We1   = (const float*)d_in[3];   // [64,256]
  const float* be1   = (const float*)d_in[4];
  const float* Kemb1 = (const float*)d_in[5];   // [256,256]
  const float* Kpool1= (const float*)d_in[6];   // [256,1024]
  const float* We2   = (const float*)d_in[7];   // [256,256]
  const float* be2   = (const float*)d_in[8];
  const float* Kemb2 = (const float*)d_in[9];   // [256,256]
  const float* Kpool2= (const float*)d_in[10];  // [256,512]
  const float* We3   = (const float*)d_in[11];  // [256,128]
  const float* be3   = (const float*)d_in[12];
  const float* Wd0   = (const float*)d_in[13];  // [64,256]
  const float* bd0   = (const float*)d_in[14];
  const float* Wd1   = (const float*)d_in[15];  // [256,256]
  const float* bd1   = (const float*)d_in[16];
  const float* Wd2   = (const float*)d_in[17];  // [256,256]
  const float* bd2   = (const float*)d_in[18];
  const float* Wdf   = (const float*)d_in[19];  // [256,64]
  const float* bdf   = (const float*)d_in[20];

  float* out = (float*)d_out;                 // [8,2048,64]
  float* out_mean = out + (long long)8 * 2048 * 64;
  float* out_lv = out_mean + (long long)8 * 512 * 64;

  // ---- workspace overlay (floats) ----
  float* W = (float*)d_ws;
  float* s1   = W;                  // 16,777,216  [8,2048,1024] persistent
  float* tmpA = W + 16777216;       // 16,777,216  big temp (tmp3/AS1/d4)
  float* A1   = W + 33554432;       //  8,388,608  [8,1024,1024] persistent
  float* s2   = W + 41943040;       //  4,194,304  [8,1024,512] persistent
  float* zb   = W + 46137344;       //  4,194,304  z1/z2/d2
  float* h1   = W + 50331648;       //  4,194,304  h1/h2/d3
  float* tB   = W + 54525952;       //  4,194,304  temp
  float* tC   = W + 58720256;       //  2,097,152  temp
  float* tD   = W + 60817408;       //  1,048,576  temp
  float* h3   = W + 61865984;       //    524,288  [8,512,128]
  float* zlat = W + 62390272;       //    262,144  [8,512,64]
  float* A2   = W + 62652416;       //  2,097,152  [8,512,512]
  // total: 64,749,568 floats = 258,998,272 bytes
  (void)ws_size; (void)n_in; (void)in_sizes; (void)out_size;

  const long long SN_H  = 2048LL * 256;   // [2048,256]
  const long long SN_K1 = 2048LL * 1024;  // [2048,1024]
  const long long SK1_H = 1024LL * 256;
  const long long SK1_K2= 1024LL * 512;
  const long long SK2_H = 512LL * 256;

  // ---------------- encode ----------------
  // E1: tB = x @ We1                       [B,2048,256]
  gemm(stream, x, We1, nullptr, tB, 2048, 256, 64, 2048LL * 64, 0, SN_H, 0, 0);
  // E2: h1 = relu(A0 @ tB + be1)
  gemm(stream, adj, tB, be1, h1, 2048, 256, 2048, 0, SN_H, SN_H, 0, 1);
  // P1a: tB = h1 @ Kemb1
  gemm(stream, h1, Kemb1, nullptr, tB, 2048, 256, 256, SN_H, 0, SN_H, 0, 0);
  // P1b: zb = A0 @ tB                      (z1)
  gemm(stream, adj, tB, nullptr, zb, 2048, 256, 2048, 0, SN_H, SN_H, 0, 0);
  // P1c: tmpA = h1 @ Kpool1                [B,2048,1024]
  gemm(stream, h1, Kpool1, nullptr, tmpA, 2048, 1024, 256, SN_H, 0, SN_K1, 0, 0);
  // P1d: s1 = A0 @ tmpA
  gemm(stream, adj, tmpA, nullptr, s1, 2048, 1024, 2048, 0, SN_K1, SN_K1, 0, 0);
  // P1e: softmax rows
  softmax_rows_k<<<dim3(BATCH * 2048), dim3(256), 0, stream>>>(s1, 1024);
  // P1f: tB = s1^T @ zb                    (xp1 [B,1024,256])
  gemm(stream, s1, zb, nullptr, tB, 1024, 256, 2048, SN_K1, SN_H, SK1_H, 1, 0);
  // P1g: tmpA = A0 @ s1                    (AS1)
  gemm(stream, adj, s1, nullptr, tmpA, 2048, 1024, 2048, 0, SN_K1, SN_K1, 0, 0);
  // P1h: A1 = s1^T @ tmpA                  [B,1024,1024]
  gemm(stream, s1, tmpA, nullptr, A1, 1024, 1024, 2048, SN_K1, SN_K1, 1024LL * 1024, 1, 0);
  // E3: tC = xp1 @ We2 ; h2 = relu(A1 @ tC + be2)  (h2 in h1 region)
  gemm(stream, tB, We2, nullptr, tC, 1024, 256, 256, SK1_H, 0, SK1_H, 0, 0);
  gemm(stream, A1, tC, be2, h1, 1024, 256, 1024, 1024LL * 1024, SK1_H, SK1_H, 0, 1);
  // P2a: tC = h2 @ Kemb2 ; zb = A1 @ tC    (z2)
  gemm(stream, h1, Kemb2, nullptr, tC, 1024, 256, 256, SK1_H, 0, SK1_H, 0, 0);
  gemm(stream, A1, tC, nullptr, zb, 1024, 256, 1024, 1024LL * 1024, SK1_H, SK1_H, 0, 0);
  // P2c: tB = h2 @ Kpool2 ; s2 = A1 @ tB ; softmax
  gemm(stream, h1, Kpool2, nullptr, tB, 1024, 512, 256, SK1_H, 0, SK1_K2, 0, 0);
  gemm(stream, A1, tB, nullptr, s2, 1024, 512, 1024, 1024LL * 1024, SK1_K2, SK1_K2, 0, 0);
  softmax_rows_k<<<dim3(BATCH * 1024), dim3(256), 0, stream>>>(s2, 512);
  // P2f: tC = s2^T @ zb                    (xp2 [B,512,256])
  gemm(stream, s2, zb, nullptr, tC, 512, 256, 1024, SK1_K2, SK1_H, SK2_H, 1, 0);
  // P2g: tB = A1 @ s2                      (AS2)
  gemm(stream, A1, s2, nullptr, tB, 1024, 512, 1024, 1024LL * 1024, SK1_K2, SK1_K2, 0, 0);
  // P2h: A2 = s2^T @ tB                    [B,512,512]
  gemm(stream, s2, tB, nullptr, A2, 512, 512, 1024, SK1_K2, SK1_K2, 512LL * 512, 1, 0);
  // E5: tD = xp2 @ We3 ; h3 = A2 @ tD + be3
  gemm(stream, tC, We3, nullptr, tD, 512, 128, 256, SK2_H, 0, 512LL * 128, 0, 0);
  gemm(stream, A2, tD, be3, h3, 512, 128, 512, 512LL * 512, 512LL * 128, 512LL * 128, 0, 0);
  // reparameterize
  reparam_k<<<dim3((8 * 512 * 64 + 255) / 256), dim3(256), 0, stream>>>(
      h3, eps, out_mean, out_lv, zlat, 8 * 512 * 64);

  // ---------------- decode ----------------
  // D0: tC = zlat @ Wd0 ; tD = relu(A2 @ tC + bd0)   (d0 [B,512,256])
  gemm(stream, zlat, Wd0, nullptr, tC, 512, 256, 64, 512LL * 64, 0, SK2_H, 0, 0);
  gemm(stream, A2, tC, bd0, tD, 512, 256, 512, 512LL * 512, SK2_H, SK2_H, 0, 1);
  // U2: tB = s2 @ tD                        (d1 [B,1024,256])
  gemm(stream, s2, tD, nullptr, tB, 1024, 256, 512, SK1_K2, SK2_H, SK1_H, 0, 0);
  // D1: tC = tB @ Wd1 ; zb = relu(A1 @ tC + bd1)     (d2)
  gemm(stream, tB, Wd1, nullptr, tC, 1024, 256, 256, SK1_H, 0, SK1_H, 0, 0);
  gemm(stream, A1, tC, bd1, zb, 1024, 256, 1024, 1024LL * 1024, SK1_H, SK1_H, 0, 1);
  // U1: h1 = s1 @ zb                        (d3 [B,2048,256])
  gemm(stream, s1, zb, nullptr, h1, 2048, 256, 1024, SN_K1, SK1_H, SN_H, 0, 0);
  // D2: tB = h1 @ Wd2 ; tmpA = relu(A0 @ tB + bd2)   (d4)
  gemm(stream, h1, Wd2, nullptr, tB, 2048, 256, 256, SN_H, 0, SN_H, 0, 0);
  gemm(stream, adj, tB, bd2, tmpA, 2048, 256, 2048, 0, SN_H, SN_H, 0, 1);
  // DF: tD = tmpA @ Wdf ; out = softplus(A0 @ tD + bdf)
  gemm(stream, tmpA, Wdf, nullptr, tD, 2048, 64, 256, SN_H, 0, 2048LL * 64, 0, 0);
  gemm(stream, adj, tD, bdf, out, 2048, 64, 2048, 0, 2048LL * 64, 2048LL * 64, 0, 2);
}

// Round 2
// 1375.050 us; speedup vs baseline: 2.9649x; 2.9649x over previous
//
#include <hip/hip_runtime.h>
#include <math.h>

#define BATCH 8
#define LSTRIDE 72

typedef __attribute__((ext_vector_type(8))) short short8;
typedef __attribute__((ext_vector_type(4))) float f32x4;

__device__ __forceinline__ unsigned short f2b(float f) {
  union { float f; unsigned u; } v; v.f = f;
  unsigned r = v.u + 0x7fffu + ((v.u >> 16) & 1u);
  return (unsigned short)(r >> 16);
}
__device__ __forceinline__ float b2f(unsigned short h) {
  union { unsigned u; float f; } v; v.u = ((unsigned)h) << 16;
  return v.f;
}

union U16x8 { uint4 v; unsigned short s[8]; };

// element index of logical (row r, col k) in a [128][64] tile stored with
// stride LSTRIDE and 16B-cell XOR swizzle (cell ^= (r>>3)&7).
__device__ __forceinline__ int lidx(int r, int k) {
  return r * LSTRIDE + ((((k >> 3) ^ ((r >> 3) & 7)) << 3) | (k & 7));
}

// ---- staging: A direct ([M,K] row-major tile 128x64 at (m0,k0)) ----
__device__ __forceinline__ void stage_N(const unsigned short* __restrict__ src,
                                        int ld, int m0, int k0, int t,
                                        unsigned short* Ls) {
  const int ar = t >> 3;          // 0..31
  const int ac8 = t & 7;          // cell 0..7 (8 elems each)
#pragma unroll
  for (int p = 0; p < 4; ++p) {
    const int row = p * 32 + ar;
    const uint4 v = *(const uint4*)(src + (long long)(m0 + row) * ld + k0 + ac8 * 8);
    *(uint4*)&Ls[lidx(row, ac8 * 8)] = v;
  }
}

// ---- staging: transpose ([K,X] row-major -> LDS [x][k] tile 128x64 at (x0,k0)) ----
__device__ __forceinline__ void stage_T(const unsigned short* __restrict__ src,
                                        int ld, int x0, int k0, int X, int t,
                                        unsigned short* Ls) {
  const int xc = (t & 15) * 8;    // x chunk 0..120
  const int g = t >> 4;           // 0..15
  const int kc = g * 4;           // k chunk 0..60
  U16x8 r0, r1, r2, r3;
  if (x0 + xc < X) {
    const unsigned short* p = src + (long long)(k0 + kc) * ld + x0 + xc;
    r0.v = *(const uint4*)p;
    r1.v = *(const uint4*)(p + ld);
    r2.v = *(const uint4*)(p + 2 * ld);
    r3.v = *(const uint4*)(p + 3 * ld);
  } else {
    r0.v = r1.v = r2.v = r3.v = make_uint4(0u, 0u, 0u, 0u);
  }
#pragma unroll
  for (int m = 0; m < 8; ++m) {
    const int x = xc + m;
    ushort4 w;
    w.x = r0.s[m]; w.y = r1.s[m]; w.z = r2.s[m]; w.w = r3.s[m];
    *(ushort4*)&Ls[lidx(x, kc)] = w;
  }
}

// ---------------- MFMA GEMM: C = act(op(A)@B + bias) ----------------
// A: bf16 [M,K] (TRANSA=0) or [K,M] (TRANSA=1). B: bf16 [K,N]. C: bf16 or f32.
// M%128==0, K%64==0, N: multiple of 8 (col-guarded). batch via elem strides.
template <int TRANSA, int ACT, bool OUTF32, bool HASBIAS>
__global__ __launch_bounds__(256) void mm_k(
    const unsigned short* __restrict__ A, const unsigned short* __restrict__ B,
    const float* __restrict__ bias, void* __restrict__ Cv,
    int M, int N, int K, long long sA, long long sB, long long sC) {
  __shared__ unsigned short As[128 * LSTRIDE];
  __shared__ unsigned short Bs[128 * LSTRIDE];

  const int b = blockIdx.z;
  A += (long long)b * sA;
  B += (long long)b * sB;
  const int m0 = blockIdx.y * 128, n0 = blockIdx.x * 128;
  const int t = threadIdx.x;
  const int lane = t & 63, w = t >> 6;
  const int wm = (w >> 1) * 64, wn = (w & 1) * 64;
  const int l15 = lane & 15, lg = lane >> 4;

  f32x4 acc[4][4];
#pragma unroll
  for (int i = 0; i < 4; ++i)
#pragma unroll
    for (int j = 0; j < 4; ++j) acc[i][j] = (f32x4){0.f, 0.f, 0.f, 0.f};

  for (int k0 = 0; k0 < K; k0 += 64) {
    if (TRANSA == 0)
      stage_N(A, K, m0, k0, t, As);
    else
      stage_T(A, M, m0, k0, M, t, As);
    stage_T(B, N, n0, k0, N, t, Bs);
    __syncthreads();

#pragma unroll
    for (int kk = 0; kk < 2; ++kk) {
      const int ko = kk * 32 + lg * 8;
      short8 af[4], bfv[4];
#pragma unroll
      for (int i = 0; i < 4; ++i)
        af[i] = *(const short8*)&As[lidx(wm + i * 16 + l15, ko)];
#pragma unroll
      for (int i = 0; i < 4; ++i)
        bfv[i] = *(const short8*)&Bs[lidx(wn + i * 16 + l15, ko)];
#pragma unroll
      for (int i = 0; i < 4; ++i)
#pragma unroll
        for (int j = 0; j < 4; ++j)
          acc[i][j] = __builtin_amdgcn_mfma_f32_16x16x32_bf16(af[i], bfv[j],
                                                              acc[i][j], 0, 0, 0);
    }
    __syncthreads();
  }

  // epilogue: C/D layout col=lane&15, row=(lane>>4)*4+e
  const long long cb = (long long)b * sC;
#pragma unroll
  for (int fi = 0; fi < 4; ++fi)
#pragma unroll
    for (int fj = 0; fj < 4; ++fj) {
      const int col = n0 + wn + fj * 16 + l15;
      if (col < N) {
        const float bsv = HASBIAS ? bias[col] : 0.0f;
#pragma unroll
        for (int e = 0; e < 4; ++e) {
          const int row = m0 + wm + fi * 16 + lg * 4 + e;
          float v = acc[fi][fj][e] + bsv;
          if (ACT == 1) v = fmaxf(v, 0.0f);
          if (ACT == 2) v = (v > 20.0f) ? v : log1pf(expf(v));
          const long long o = cb + (long long)row * N + col;
          if (OUTF32)
            ((float*)Cv)[o] = v;
          else
            ((unsigned short*)Cv)[o] = f2b(v);
        }
      }
    }
}

// ---------------- bf16 row softmax (in place) ----------------
template <int PT>
__global__ __launch_bounds__(256) void softmax_k(unsigned short* __restrict__ x) {
  __shared__ float red[256];
  const long long row = blockIdx.x;
  unsigned short* p = x + row * (PT * 256);
  const int t = threadIdx.x;
  float v[PT];
#pragma unroll
  for (int i = 0; i < PT; ++i) v[i] = b2f(p[t + i * 256]);
  float mx = v[0];
#pragma unroll
  for (int i = 1; i < PT; ++i) mx = fmaxf(mx, v[i]);
  red[t] = mx;
  __syncthreads();
  for (int s = 128; s; s >>= 1) {
    if (t < s) red[t] = fmaxf(red[t], red[t + s]);
    __syncthreads();
  }
  mx = red[0];
  __syncthreads();
  float sum = 0.0f;
#pragma unroll
  for (int i = 0; i < PT; ++i) {
    v[i] = expf(v[i] - mx);
    sum += v[i];
  }
  red[t] = sum;
  __syncthreads();
  for (int s = 128; s; s >>= 1) {
    if (t < s) red[t] += red[t + s];
    __syncthreads();
  }
  const float inv = 1.0f / red[0];
#pragma unroll
  for (int i = 0; i < PT; ++i) p[t + i * 256] = f2b(v[i] * inv);
}

// ---------------- reparameterize ----------------
__global__ __launch_bounds__(256) void reparam_k(
    const float* __restrict__ h3, const float* __restrict__ eps,
    float* __restrict__ om, float* __restrict__ olv,
    unsigned short* __restrict__ z, int total) {
  const int i = blockIdx.x * 256 + threadIdx.x;
  if (i >= total) return;
  const int j = i & 63;
  const long long r = i >> 6;
  const float m = h3[r * 128 + j];
  const float lv = h3[r * 128 + 64 + j];
  om[i] = m;
  olv[i] = lv;
  z[i] = f2b(m + expf(0.5f * lv) * eps[i]);
}

// ---------------- f32 -> bf16 conversion ----------------
__global__ __launch_bounds__(256) void f2b_k(const float* __restrict__ s,
                                             unsigned short* __restrict__ d, int n4) {
  const int i = blockIdx.x * 256 + threadIdx.x;
  if (i < n4) {
    const float4 v = ((const float4*)s)[i];
    ushort4 o;
    o.x = f2b(v.x); o.y = f2b(v.y); o.z = f2b(v.z); o.w = f2b(v.w);
    ((ushort4*)d)[i] = o;
  }
}

// ---------------- host dispatch ----------------
static void mm(hipStream_t st, const unsigned short* A, const unsigned short* B,
               const float* bias, void* C, int M, int N, int K, long long sA,
               long long sB, long long sC, int transA, int act, bool outf32) {
  dim3 g((N + 127) / 128, M / 128, BATCH), blk(256);
  if (transA)
    mm_k<1, 0, false, false><<<g, blk, 0, st>>>(A, B, nullptr, C, M, N, K, sA, sB, sC);
  else if (outf32 && act == 2)
    mm_k<0, 2, true, true><<<g, blk, 0, st>>>(A, B, bias, C, M, N, K, sA, sB, sC);
  else if (outf32)
    mm_k<0, 0, true, true><<<g, blk, 0, st>>>(A, B, bias, C, M, N, K, sA, sB, sC);
  else if (act == 1)
    mm_k<0, 1, false, true><<<g, blk, 0, st>>>(A, B, bias, C, M, N, K, sA, sB, sC);
  else
    mm_k<0, 0, false, false><<<g, blk, 0, st>>>(A, B, nullptr, C, M, N, K, sA, sB, sC);
}

extern "C" void kernel_launch(void* const* d_in, const int* in_sizes, int n_in,
                              void* d_out, int out_size, void* d_ws, size_t ws_size,
                              hipStream_t stream) {
  const float* x      = (const float*)d_in[0];
  const float* eps    = (const float*)d_in[1];
  const float* adj    = (const float*)d_in[2];
  const float* We1    = (const float*)d_in[3];
  const float* be1    = (const float*)d_in[4];
  const float* Kemb1  = (const float*)d_in[5];
  const float* Kpool1 = (const float*)d_in[6];
  const float* We2    = (const float*)d_in[7];
  const float* be2    = (const float*)d_in[8];
  const float* Kemb2  = (const float*)d_in[9];
  const float* Kpool2 = (const float*)d_in[10];
  const float* We3    = (const float*)d_in[11];
  const float* be3    = (const float*)d_in[12];
  const float* Wd0    = (const float*)d_in[13];
  const float* bd0    = (const float*)d_in[14];
  const float* Wd1    = (const float*)d_in[15];
  const float* bd1    = (const float*)d_in[16];
  const float* Wd2    = (const float*)d_in[17];
  const float* bd2    = (const float*)d_in[18];
  const float* Wdf    = (const float*)d_in[19];
  const float* bdf    = (const float*)d_in[20];
  (void)in_sizes; (void)n_in; (void)ws_size; (void)out_size;

  float* out = (float*)d_out;                       // [8,2048,64]
  float* out_mean = out + (long long)8 * 2048 * 64;
  float* out_lv = out_mean + (long long)8 * 512 * 64;

  // ---- workspace overlay (byte offsets, 256-aligned) ----
  char* base = (char*)d_ws;
  size_t off = 0;
  auto alloc = [&](size_t bytes) {
    char* p = base + off;
    off += (bytes + 255) & ~(size_t)255;
    return p;
  };
  unsigned short* adjb = (unsigned short*)alloc(2048LL * 2048 * 2);
  unsigned short* xb   = (unsigned short*)alloc(8LL * 2048 * 64 * 2);
  unsigned short* s1b  = (unsigned short*)alloc(8LL * 2048 * 1024 * 2);
  unsigned short* tmp  = (unsigned short*)alloc(8LL * 2048 * 1024 * 2);
  unsigned short* A1b  = (unsigned short*)alloc(8LL * 1024 * 1024 * 2);
  unsigned short* s2b  = (unsigned short*)alloc(8LL * 1024 * 512 * 2);
  unsigned short* zbb  = (unsigned short*)alloc(8LL * 2048 * 256 * 2);
  unsigned short* h1b  = (unsigned short*)alloc(8LL * 2048 * 256 * 2);
  unsigned short* tBb  = (unsigned short*)alloc(8LL * 2048 * 256 * 2);
  unsigned short* tCb  = (unsigned short*)alloc(8LL * 1024 * 256 * 2);
  unsigned short* tDb  = (unsigned short*)alloc(8LL * 2048 * 64 * 2 * 2);
  unsigned short* A2b  = (unsigned short*)alloc(8LL * 512 * 512 * 2);
  float*          h3f  = (float*)alloc(8LL * 512 * 128 * 4);
  unsigned short* zlb  = (unsigned short*)alloc(8LL * 512 * 64 * 2);
  unsigned short* We1b = (unsigned short*)alloc(64 * 256 * 2);
  unsigned short* Ke1b = (unsigned short*)alloc(256 * 256 * 2);
  unsigned short* Kp1b = (unsigned short*)alloc(256 * 1024 * 2);
  unsigned short* We2b = (unsigned short*)alloc(256 * 256 * 2);
  unsigned short* Ke2b = (unsigned short*)alloc(256 * 256 * 2);
  unsigned short* Kp2b = (unsigned short*)alloc(256 * 512 * 2);
  unsigned short* We3b = (unsigned short*)alloc(256 * 128 * 2);
  unsigned short* Wd0b = (unsigned short*)alloc(64 * 256 * 2);
  unsigned short* Wd1b = (unsigned short*)alloc(256 * 256 * 2);
  unsigned short* Wd2b = (unsigned short*)alloc(256 * 256 * 2);
  unsigned short* Wdfb = (unsigned short*)alloc(256 * 64 * 2);

  auto conv = [&](const float* s, unsigned short* d, long long n) {
    const int n4 = (int)(n / 4);
    f2b_k<<<dim3((n4 + 255) / 256), dim3(256), 0, stream>>>(s, d, n4);
  };
  conv(x, xb, 8LL * 2048 * 64);
  conv(adj, adjb, 2048LL * 2048);
  conv(We1, We1b, 64 * 256);   conv(Kemb1, Ke1b, 256 * 256);
  conv(Kpool1, Kp1b, 256 * 1024); conv(We2, We2b, 256 * 256);
  conv(Kemb2, Ke2b, 256 * 256);  conv(Kpool2, Kp2b, 256 * 512);
  conv(We3, We3b, 256 * 128);    conv(Wd0, Wd0b, 64 * 256);
  conv(Wd1, Wd1b, 256 * 256);    conv(Wd2, Wd2b, 256 * 256);
  conv(Wdf, Wdfb, 256 * 64);

  const long long SN_H = 2048LL * 256, SN_K1 = 2048LL * 1024;
  const long long SK1_H = 1024LL * 256, SK1_K2 = 1024LL * 512, SK2_H = 512LL * 256;

  // ---------------- encode ----------------
  mm(stream, xb, We1b, nullptr, tBb, 2048, 256, 64, 2048LL * 64, 0, SN_H, 0, 0, false);     // E1
  mm(stream, adjb, tBb, be1, h1b, 2048, 256, 2048, 0, SN_H, SN_H, 0, 1, false);             // E2
  mm(stream, h1b, Ke1b, nullptr, tBb, 2048, 256, 256, SN_H, 0, SN_H, 0, 0, false);          // P1a
  mm(stream, adjb, tBb, nullptr, zbb, 2048, 256, 2048, 0, SN_H, SN_H, 0, 0, false);         // P1b z1
  mm(stream, h1b, Kp1b, nullptr, tmp, 2048, 1024, 256, SN_H, 0, SN_K1, 0, 0, false);        // P1c
  mm(stream, adjb, tmp, nullptr, s1b, 2048, 1024, 2048, 0, SN_K1, SN_K1, 0, 0, false);      // P1d
  softmax_k<4><<<dim3(BATCH * 2048), dim3(256), 0, stream>>>(s1b);                          // P1e
  mm(stream, s1b, zbb, nullptr, tBb, 1024, 256, 2048, SN_K1, SN_H, SK1_H, 1, 0, false);     // P1f xp1
  mm(stream, adjb, s1b, nullptr, tmp, 2048, 1024, 2048, 0, SN_K1, SN_K1, 0, 0, false);      // P1g AS1
  mm(stream, s1b, tmp, nullptr, A1b, 1024, 1024, 2048, SN_K1, SN_K1, 1024LL * 1024, 1, 0, false); // P1h
  mm(stream, tBb, We2b, nullptr, tCb, 1024, 256, 256, SK1_H, 0, SK1_H, 0, 0, false);        // E3a
  mm(stream, A1b, tCb, be2, h1b, 1024, 256, 1024, 1024LL * 1024, SK1_H, SK1_H, 0, 1, false);// E3b
  mm(stream, h1b, Ke2b, nullptr, tCb, 1024, 256, 256, SK1_H, 0, SK1_H, 0, 0, false);        // P2a
  mm(stream, A1b, tCb, nullptr, zbb, 1024, 256, 1024, 1024LL * 1024, SK1_H, SK1_H, 0, 0, false); // P2b z2
  mm(stream, h1b, Kp2b, nullptr, tBb, 1024, 512, 256, SK1_H, 0, SK1_K2, 0, 0, false);       // P2c
  mm(stream, A1b, tBb, nullptr, s2b, 1024, 512, 1024, 1024LL * 1024, SK1_K2, SK1_K2, 0, 0, false); // P2d
  softmax_k<2><<<dim3(BATCH * 1024), dim3(256), 0, stream>>>(s2b);                          // P2e
  mm(stream, s2b, zbb, nullptr, tCb, 512, 256, 1024, SK1_K2, SK1_H, SK2_H, 1, 0, false);    // P2f xp2
  mm(stream, A1b, s2b, nullptr, tBb, 1024, 512, 1024, 1024LL * 1024, SK1_K2, SK1_K2, 0, 0, false); // P2g AS2
  mm(stream, s2b, tBb, nullptr, A2b, 512, 512, 1024, SK1_K2, SK1_K2, 512LL * 512, 1, 0, false);    // P2h
  mm(stream, tCb, We3b, nullptr, tDb, 512, 128, 256, SK2_H, 0, 512LL * 128, 0, 0, false);   // E5a
  mm(stream, A2b, tDb, be3, h3f, 512, 128, 512, 512LL * 512, 512LL * 128, 512LL * 128, 0, 0, true); // E5b
  reparam_k<<<dim3((8 * 512 * 64 + 255) / 256), dim3(256), 0, stream>>>(
      h3f, eps, out_mean, out_lv, zlb, 8 * 512 * 64);

  // ---------------- decode ----------------
  mm(stream, zlb, Wd0b, nullptr, tCb, 512, 256, 64, 512LL * 64, 0, SK2_H, 0, 0, false);     // D0a
  mm(stream, A2b, tCb, bd0, tDb, 512, 256, 512, 512LL * 512, SK2_H, SK2_H, 0, 1, false);    // D0b d0
  mm(stream, s2b, tDb, nullptr, tBb, 1024, 256, 512, SK1_K2, SK2_H, SK1_H, 0, 0, false);    // U2 d1
  mm(stream, tBb, Wd1b, nullptr, tCb, 1024, 256, 256, SK1_H, 0, SK1_H, 0, 0, false);        // D1a
  mm(stream, A1b, tCb, bd1, zbb, 1024, 256, 1024, 1024LL * 1024, SK1_H, SK1_H, 0, 1, false);// D1b d2
  mm(stream, s1b, zbb, nullptr, h1b, 2048, 256, 1024, SN_K1, SK1_H, SN_H, 0, 0, false);     // U1 d3
  mm(stream, h1b, Wd2b, nullptr, tBb, 2048, 256, 256, SN_H, 0, SN_H, 0, 0, false);          // D2a
  mm(stream, adjb, tBb, bd2, tmp, 2048, 256, 2048, 0, SN_H, SN_H, 0, 1, false);             // D2b d4
  mm(stream, tmp, Wdfb, nullptr, tDb, 2048, 64, 256, SN_H, 0, 2048LL * 64, 0, 0, false);    // DFa
  mm(stream, adjb, tDb, bdf, out, 2048, 64, 2048, 0, 2048LL * 64, 2048LL * 64, 0, 2, true); // DF
}

// Round 3
// 820.447 us; speedup vs baseline: 4.9690x; 1.6760x over previous
//
#include <hip/hip_runtime.h>
#include <math.h>

#define BATCH 8

typedef __attribute__((ext_vector_type(8))) short short8;
typedef __attribute__((ext_vector_type(4))) float f32x4;

__device__ __forceinline__ unsigned short f2b(float f) {
  union { float f; unsigned u; } v; v.f = f;
  unsigned r = v.u + 0x7fffu + ((v.u >> 16) & 1u);
  return (unsigned short)(r >> 16);
}
__device__ __forceinline__ float b2f(unsigned short h) {
  union { unsigned u; float f; } v; v.u = ((unsigned)h) << 16;
  return v.f;
}

__device__ __forceinline__ void gload16(const unsigned short* g, unsigned short* l) {
  __builtin_amdgcn_global_load_lds(
      (const __attribute__((address_space(1))) unsigned int*)g,
      (__attribute__((address_space(3))) unsigned int*)l, 16, 0, 0);
}

// LDS tile [rows][64] linear, XOR swizzle: cell (16B) index ^= (row&7).
__device__ __forceinline__ int lidx2(int r, int ko) {
  return r * 64 + ((((ko >> 3) ^ (r & 7)) << 3));
}

// ---------------- MFMA GEMM (all-direct staging) ----------------
// C = act(A@B + bias). A bf16 phys [M][K] ld=K. B bf16 phys [N][K] ld=K
// (i.e. B is the mathematical B stored transposed). C: per OUT mode.
// OUT: 0 = bf16 row-major [M][N], 1 = bf16 transposed [N][M], 2 = f32 [M][N].
// M%128==0, K%64==0, N%TN==0 (TN = 128 or 64).
template <int TN, int ACT, int OUT, bool HASBIAS>
__global__ __launch_bounds__(256) void mm_k(
    const unsigned short* __restrict__ A, const unsigned short* __restrict__ B,
    const float* __restrict__ bias, void* __restrict__ Cv,
    int M, int N, int K, long long sA, long long sB, long long sC) {
  constexpr int JF = TN / 32;  // frag cols per wave
  __shared__ unsigned short As[128 * 64];
  __shared__ unsigned short Bs[TN * 64];

  const int b = blockIdx.z;
  A += (long long)b * sA;
  B += (long long)b * sB;
  const int m0 = blockIdx.y * 128, n0 = blockIdx.x * TN;
  const int t = threadIdx.x, lane = t & 63, w = t >> 6;
  const int wm = (w >> 1) * 64, wn = (w & 1) * (TN / 2);
  const int l15 = lane & 15, lg = lane >> 4;
  const int lrow = lane >> 3;                 // row within 8-row group
  const int gcell = (((lane & 7) ^ lrow) << 3);  // pre-swizzled source cell

  f32x4 acc[4][JF];
#pragma unroll
  for (int i = 0; i < 4; ++i)
#pragma unroll
    for (int j = 0; j < JF; ++j) acc[i][j] = (f32x4){0.f, 0.f, 0.f, 0.f};

  for (int k0 = 0; k0 < K; k0 += 64) {
    // A tile: 16 groups of 8 rows, 4 per wave
#pragma unroll
    for (int i = 0; i < 4; ++i) {
      const int g = w * 4 + i;
      gload16(A + (long long)(m0 + g * 8 + lrow) * K + k0 + gcell, &As[g * 512]);
    }
    // B tile: TN/8 groups
#pragma unroll
    for (int i = 0; i < TN / 32; ++i) {
      const int g = w * (TN / 32) + i;
      gload16(B + (long long)(n0 + g * 8 + lrow) * K + k0 + gcell, &Bs[g * 512]);
    }
    __syncthreads();

#pragma unroll
    for (int kk = 0; kk < 2; ++kk) {
      const int ko = kk * 32 + lg * 8;
      short8 af[4], bf[JF];
#pragma unroll
      for (int i = 0; i < 4; ++i)
        af[i] = *(const short8*)&As[lidx2(wm + i * 16 + l15, ko)];
#pragma unroll
      for (int j = 0; j < JF; ++j)
        bf[j] = *(const short8*)&Bs[lidx2(wn + j * 16 + l15, ko)];
#pragma unroll
      for (int i = 0; i < 4; ++i)
#pragma unroll
        for (int j = 0; j < JF; ++j)
          acc[i][j] = __builtin_amdgcn_mfma_f32_16x16x32_bf16(af[i], bf[j],
                                                              acc[i][j], 0, 0, 0);
    }
    __syncthreads();
  }

  const long long cb = (long long)b * sC;
#pragma unroll
  for (int fj = 0; fj < JF; ++fj) {
    const int col = n0 + wn + fj * 16 + l15;
    const float bsv = HASBIAS ? bias[col] : 0.0f;
#pragma unroll
    for (int fi = 0; fi < 4; ++fi) {
      const int row0 = m0 + wm + fi * 16 + lg * 4;
      if (OUT == 1) {
        unsigned short pv[4];
#pragma unroll
        for (int e = 0; e < 4; ++e) {
          float v = acc[fi][fj][e] + bsv;
          if (ACT == 1) v = fmaxf(v, 0.0f);
          if (ACT == 2) v = (v > 20.0f) ? v : log1pf(expf(v));
          pv[e] = f2b(v);
        }
        ushort4 pk; pk.x = pv[0]; pk.y = pv[1]; pk.z = pv[2]; pk.w = pv[3];
        *(ushort4*)&((unsigned short*)Cv)[cb + (long long)col * M + row0] = pk;
      } else {
#pragma unroll
        for (int e = 0; e < 4; ++e) {
          float v = acc[fi][fj][e] + bsv;
          if (ACT == 1) v = fmaxf(v, 0.0f);
          if (ACT == 2) v = (v > 20.0f) ? v : log1pf(expf(v));
          const long long o = cb + (long long)(row0 + e) * N + col;
          if (OUT == 2) ((float*)Cv)[o] = v;
          else ((unsigned short*)Cv)[o] = f2b(v);
        }
      }
    }
  }
}

// ---------------- column softmax in place: x [B][R][C], softmax over R ----
__global__ __launch_bounds__(256) void colsoftmax_k(unsigned short* __restrict__ x,
                                                    int R, int C) {
  __shared__ float sm[4][64], ss[4][64];
  const int t = threadIdx.x;
  const int c = blockIdx.x * 64 + (t & 63);
  const int chunk = t >> 6;
  const int Rc = R >> 2;
  const long long base = (long long)blockIdx.y * R * C + c;
  float m = -1e30f, s = 0.f;
  for (int r = chunk * Rc; r < (chunk + 1) * Rc; ++r) {
    const float v = b2f(x[base + (long long)r * C]);
    const float nm = fmaxf(m, v);
    s = s * expf(m - nm) + expf(v - nm);
    m = nm;
  }
  sm[chunk][t & 63] = m; ss[chunk][t & 63] = s;
  __syncthreads();
  float M = sm[0][t & 63], S = ss[0][t & 63];
#pragma unroll
  for (int i = 1; i < 4; ++i) {
    const float m2 = sm[i][t & 63], s2 = ss[i][t & 63];
    const float nm = fmaxf(M, m2);
    S = S * expf(M - nm) + s2 * expf(m2 - nm);
    M = nm;
  }
  const float inv = 1.0f / S;
  for (int r = chunk * Rc; r < (chunk + 1) * Rc; ++r) {
    const long long idx = base + (long long)r * C;
    x[idx] = f2b(expf(b2f(x[idx]) - M) * inv);
  }
}

// ---------------- transpose (+optional f32->bf16): src [B][R][C] -> dst [B][C][R]
template <bool F32IN>
__global__ __launch_bounds__(256) void trans_k(const void* __restrict__ srcv,
                                               unsigned short* __restrict__ dst,
                                               int R, int C, long long sIn,
                                               long long sOut) {
  __shared__ unsigned short L[64][65];
  const int b = blockIdx.z;
  const int r0 = blockIdx.y * 64, c0 = blockIdx.x * 64;
  const int t = threadIdx.x;
  const int lr = t >> 4, lc = (t & 15) * 4;
#pragma unroll
  for (int i = 0; i < 4; ++i) {
    const int rr = r0 + lr + 16 * i;
    if (F32IN) {
      const float* s = (const float*)srcv + (long long)b * sIn;
      const float4 v = *(const float4*)&s[(long long)rr * C + c0 + lc];
      L[lr + 16 * i][lc + 0] = f2b(v.x);
      L[lr + 16 * i][lc + 1] = f2b(v.y);
      L[lr + 16 * i][lc + 2] = f2b(v.z);
      L[lr + 16 * i][lc + 3] = f2b(v.w);
    } else {
      const unsigned short* s = (const unsigned short*)srcv + (long long)b * sIn;
      const ushort4 v = *(const ushort4*)&s[(long long)rr * C + c0 + lc];
      L[lr + 16 * i][lc + 0] = v.x;
      L[lr + 16 * i][lc + 1] = v.y;
      L[lr + 16 * i][lc + 2] = v.z;
      L[lr + 16 * i][lc + 3] = v.w;
    }
  }
  __syncthreads();
#pragma unroll
  for (int i = 0; i < 4; ++i) {
    ushort4 o;
    o.x = L[lc + 0][lr + 16 * i];
    o.y = L[lc + 1][lr + 16 * i];
    o.z = L[lc + 2][lr + 16 * i];
    o.w = L[lc + 3][lr + 16 * i];
    *(ushort4*)&dst[(long long)b * sOut + (long long)(c0 + lr + 16 * i) * R + r0 + lc] = o;
  }
}

// ---------------- f32 -> bf16 ----------------
__global__ __launch_bounds__(256) void f2b_k(const float* __restrict__ s,
                                             unsigned short* __restrict__ d, int n4) {
  const int i = blockIdx.x * 256 + threadIdx.x;
  if (i < n4) {
    const float4 v = ((const float4*)s)[i];
    ushort4 o;
    o.x = f2b(v.x); o.y = f2b(v.y); o.z = f2b(v.z); o.w = f2b(v.w);
    ((ushort4*)d)[i] = o;
  }
}

// ---------------- reparameterize ----------------
__global__ __launch_bounds__(256) void reparam_k(
    const float* __restrict__ h3, const float* __restrict__ eps,
    float* __restrict__ om, float* __restrict__ olv,
    unsigned short* __restrict__ z, int total) {
  const int i = blockIdx.x * 256 + threadIdx.x;
  if (i >= total) return;
  const int j = i & 63;
  const long long r = i >> 6;
  const float m = h3[r * 128 + j];
  const float lv = h3[r * 128 + 64 + j];
  om[i] = m;
  olv[i] = lv;
  z[i] = f2b(m + expf(0.5f * lv) * eps[i]);
}

// ---------------- host dispatch ----------------
static void mm(hipStream_t st, const unsigned short* A, const unsigned short* B,
               const float* bias, void* C, int M, int N, int K, long long sA,
               long long sB, long long sC, int act, int outmode, int tn) {
  dim3 g(N / tn, M / 128, BATCH), blk(256);
  if (tn == 64) {
    if (outmode == 0)
      mm_k<64, 0, 0, false><<<g, blk, 0, st>>>(A, B, nullptr, C, M, N, K, sA, sB, sC);
    else if (outmode == 1)
      mm_k<64, 0, 1, false><<<g, blk, 0, st>>>(A, B, nullptr, C, M, N, K, sA, sB, sC);
    else
      mm_k<64, 2, 2, true><<<g, blk, 0, st>>>(A, B, bias, C, M, N, K, sA, sB, sC);
  } else if (outmode == 0) {
    if (act == 1)
      mm_k<128, 1, 0, true><<<g, blk, 0, st>>>(A, B, bias, C, M, N, K, sA, sB, sC);
    else
      mm_k<128, 0, 0, false><<<g, blk, 0, st>>>(A, B, nullptr, C, M, N, K, sA, sB, sC);
  } else if (outmode == 1) {
    if (act == 1)
      mm_k<128, 1, 1, true><<<g, blk, 0, st>>>(A, B, bias, C, M, N, K, sA, sB, sC);
    else
      mm_k<128, 0, 1, false><<<g, blk, 0, st>>>(A, B, nullptr, C, M, N, K, sA, sB, sC);
  } else {
    mm_k<128, 0, 2, true><<<g, blk, 0, st>>>(A, B, bias, C, M, N, K, sA, sB, sC);
  }
}

extern "C" void kernel_launch(void* const* d_in, const int* in_sizes, int n_in,
                              void* d_out, int out_size, void* d_ws, size_t ws_size,
                              hipStream_t stream) {
  const float* x      = (const float*)d_in[0];
  const float* eps    = (const float*)d_in[1];
  const float* adj    = (const float*)d_in[2];
  const float* We1    = (const float*)d_in[3];
  const float* be1    = (const float*)d_in[4];
  const float* Kemb1  = (const float*)d_in[5];
  const float* Kpool1 = (const float*)d_in[6];
  const float* We2    = (const float*)d_in[7];
  const float* be2    = (const float*)d_in[8];
  const float* Kemb2  = (const float*)d_in[9];
  const float* Kpool2 = (const float*)d_in[10];
  const float* We3    = (const float*)d_in[11];
  const float* be3    = (const float*)d_in[12];
  const float* Wd0    = (const float*)d_in[13];
  const float* bd0    = (const float*)d_in[14];
  const float* Wd1    = (const float*)d_in[15];
  const float* bd1    = (const float*)d_in[16];
  const float* Wd2    = (const float*)d_in[17];
  const float* bd2    = (const float*)d_in[18];
  const float* Wdf    = (const float*)d_in[19];
  const float* bdf    = (const float*)d_in[20];
  (void)in_sizes; (void)n_in; (void)ws_size; (void)out_size;

  float* out = (float*)d_out;
  float* out_mean = out + (long long)8 * 2048 * 64;
  float* out_lv = out_mean + (long long)8 * 512 * 64;

  char* base = (char*)d_ws;
  size_t off = 0;
  auto alloc = [&](size_t bytes) {
    char* p = base + off;
    off += (bytes + 255) & ~(size_t)255;
    return p;
  };
#define US unsigned short
  US* adjb = (US*)alloc(2048LL * 2048 * 2);
  US* xT   = (US*)alloc(8LL * 64 * 2048 * 2);
  US* Y0   = (US*)alloc(8LL * 2048 * 64 * 2);
  US* h1T  = (US*)alloc(8LL * 256 * 2048 * 2);
  US* g1   = (US*)alloc(8LL * 2048 * 256 * 2);
  US* z1T  = (US*)alloc(8LL * 256 * 2048 * 2);
  US* s1T  = (US*)alloc(8LL * 1024 * 2048 * 2);
  US* AS1  = (US*)alloc(8LL * 2048 * 1024 * 2);
  US* AS1T = (US*)alloc(8LL * 1024 * 2048 * 2);
  US* A1   = (US*)alloc(8LL * 1024 * 1024 * 2);
  US* xp1  = (US*)alloc(8LL * 1024 * 256 * 2);
  US* t1T  = (US*)alloc(8LL * 256 * 1024 * 2);
  US* h2T  = (US*)alloc(8LL * 256 * 1024 * 2);
  US* g2   = (US*)alloc(8LL * 1024 * 256 * 2);
  US* z2T  = (US*)alloc(8LL * 256 * 1024 * 2);
  US* s2T  = (US*)alloc(8LL * 512 * 1024 * 2);
  US* AS2  = (US*)alloc(8LL * 1024 * 512 * 2);
  US* AS2T = (US*)alloc(8LL * 512 * 1024 * 2);
  US* A2   = (US*)alloc(8LL * 512 * 512 * 2);
  US* xp2  = (US*)alloc(8LL * 512 * 256 * 2);
  US* t2T  = (US*)alloc(8LL * 128 * 512 * 2);
  float* h3f = (float*)alloc(8LL * 512 * 128 * 4);
  US* zlb  = (US*)alloc(8LL * 512 * 64 * 2);
  US* t3T  = (US*)alloc(8LL * 256 * 512 * 2);
  US* d0   = (US*)alloc(8LL * 512 * 256 * 2);
  US* t4T  = (US*)alloc(8LL * 256 * 512 * 2);
  US* d2   = (US*)alloc(8LL * 1024 * 256 * 2);
  US* t5T  = (US*)alloc(8LL * 256 * 1024 * 2);
  US* d4   = (US*)alloc(8LL * 2048 * 256 * 2);
  US* t6T  = (US*)alloc(8LL * 64 * 2048 * 2);
  US* We1T = (US*)alloc(256 * 64 * 2);
  US* Ke1T = (US*)alloc(256 * 256 * 2);
  US* Kp1T = (US*)alloc(1024 * 256 * 2);
  US* We2T = (US*)alloc(256 * 256 * 2);
  US* Ke2T = (US*)alloc(256 * 256 * 2);
  US* Kp2T = (US*)alloc(512 * 256 * 2);
  US* We3T = (US*)alloc(128 * 256 * 2);
  US* Wd0T = (US*)alloc(256 * 64 * 2);
  US* Wd1T = (US*)alloc(256 * 256 * 2);
  US* Wd2T = (US*)alloc(256 * 256 * 2);
  US* WdfT = (US*)alloc(64 * 256 * 2);

  // ---- input conversions ----
  f2b_k<<<dim3(2048 * 2048 / 4 / 256), dim3(256), 0, stream>>>(adj, adjb, 2048 * 2048 / 4);
  trans_k<true><<<dim3(1, 32, 8), dim3(256), 0, stream>>>(x, xT, 2048, 64,
                                                          2048LL * 64, 64LL * 2048);
  auto wt = [&](const float* w, US* wT, int R, int C) {
    trans_k<true><<<dim3(C / 64, R / 64, 1), dim3(256), 0, stream>>>(w, wT, R, C, 0, 0);
  };
  wt(We1, We1T, 64, 256);    wt(Kemb1, Ke1T, 256, 256);
  wt(Kpool1, Kp1T, 256, 1024); wt(We2, We2T, 256, 256);
  wt(Kemb2, Ke2T, 256, 256); wt(Kpool2, Kp2T, 256, 512);
  wt(We3, We3T, 256, 128);   wt(Wd0, Wd0T, 64, 256);
  wt(Wd1, Wd1T, 256, 256);   wt(Wd2, Wd2T, 256, 256);
  wt(Wdf, WdfT, 256, 64);

  const long long SxT = 64LL * 2048, SY0 = 2048LL * 64;
  const long long Sh1T = 256LL * 2048, Sg1 = 2048LL * 256;
  const long long Ss1 = 1024LL * 2048, SAS1 = 2048LL * 1024;
  const long long SA1 = 1024LL * 1024;

  // ---------------- encode ----------------
  mm(stream, adjb, xT, nullptr, Y0, 2048, 64, 2048, 0, SxT, SY0, 0, 0, 64);          // Y0 = adj@x
  mm(stream, Y0, We1T, be1, h1T, 2048, 256, 64, SY0, 0, Sh1T, 1, 1, 128);            // h1T = relu(Y0@We1+b)^T
  mm(stream, adjb, h1T, nullptr, g1, 2048, 256, 2048, 0, Sh1T, Sg1, 0, 0, 128);      // g1 = adj@h1
  mm(stream, g1, Ke1T, nullptr, z1T, 2048, 256, 256, Sg1, 0, Sh1T, 0, 1, 128);       // z1T
  mm(stream, g1, Kp1T, nullptr, s1T, 2048, 1024, 256, Sg1, 0, Ss1, 0, 1, 128);       // s1pT
  colsoftmax_k<<<dim3(32, 8), dim3(256), 0, stream>>>(s1T, 1024, 2048);              // softmax over k1
  mm(stream, adjb, s1T, nullptr, AS1, 2048, 1024, 2048, 0, Ss1, SAS1, 0, 0, 128);    // AS1 = adj@s1
  trans_k<false><<<dim3(16, 32, 8), dim3(256), 0, stream>>>(AS1, AS1T, 2048, 1024,
                                                            SAS1, Ss1);              // AS1T
  mm(stream, s1T, AS1T, nullptr, A1, 1024, 1024, 2048, Ss1, Ss1, SA1, 0, 0, 128);    // A1 = s1^T@AS1
  mm(stream, s1T, z1T, nullptr, xp1, 1024, 256, 2048, Ss1, Sh1T, 1024LL * 256, 0, 0, 128); // xp1
  mm(stream, xp1, We2T, nullptr, t1T, 1024, 256, 256, 1024LL * 256, 0, 256LL * 1024, 0, 1, 128);
  mm(stream, A1, t1T, be2, h2T, 1024, 256, 1024, SA1, 256LL * 1024, 256LL * 1024, 1, 1, 128); // h2T
  mm(stream, A1, h2T, nullptr, g2, 1024, 256, 1024, SA1, 256LL * 1024, 1024LL * 256, 0, 0, 128); // g2
  mm(stream, g2, Ke2T, nullptr, z2T, 1024, 256, 256, 1024LL * 256, 0, 256LL * 1024, 0, 1, 128);
  mm(stream, g2, Kp2T, nullptr, s2T, 1024, 512, 256, 1024LL * 256, 0, 512LL * 1024, 0, 1, 128);
  colsoftmax_k<<<dim3(16, 8), dim3(256), 0, stream>>>(s2T, 512, 1024);
  mm(stream, A1, s2T, nullptr, AS2, 1024, 512, 1024, SA1, 512LL * 1024, 1024LL * 512, 0, 0, 128); // AS2
  trans_k<false><<<dim3(8, 16, 8), dim3(256), 0, stream>>>(AS2, AS2T, 1024, 512,
                                                           1024LL * 512, 512LL * 1024);
  mm(stream, s2T, AS2T, nullptr, A2, 512, 512, 1024, 512LL * 1024, 512LL * 1024, 512LL * 512, 0, 0, 128); // A2
  mm(stream, s2T, z2T, nullptr, xp2, 512, 256, 1024, 512LL * 1024, 256LL * 1024, 512LL * 256, 0, 0, 128); // xp2
  mm(stream, xp2, We3T, nullptr, t2T, 512, 128, 256, 512LL * 256, 0, 128LL * 512, 0, 1, 128);
  mm(stream, A2, t2T, be3, h3f, 512, 128, 512, 512LL * 512, 128LL * 512, 512LL * 128, 0, 2, 128); // h3 f32
  reparam_k<<<dim3(8 * 512 * 64 / 256), dim3(256), 0, stream>>>(h3f, eps, out_mean,
                                                                out_lv, zlb, 8 * 512 * 64);

  // ---------------- decode ----------------
  mm(stream, zlb, Wd0T, nullptr, t3T, 512, 256, 64, 512LL * 64, 0, 256LL * 512, 0, 1, 128);
  mm(stream, A2, t3T, bd0, d0, 512, 256, 512, 512LL * 512, 256LL * 512, 512LL * 256, 1, 0, 128);
  mm(stream, d0, Wd1T, nullptr, t4T, 512, 256, 256, 512LL * 256, 0, 256LL * 512, 0, 1, 128);
  mm(stream, AS2, t4T, bd1, d2, 1024, 256, 512, 1024LL * 512, 256LL * 512, 1024LL * 256, 1, 0, 128);
  mm(stream, d2, Wd2T, nullptr, t5T, 1024, 256, 256, 1024LL * 256, 0, 256LL * 1024, 0, 1, 128);
  mm(stream, AS1, t5T, bd2, d4, 2048, 256, 1024, SAS1, 256LL * 1024, 2048LL * 256, 1, 0, 128);
  mm(stream, d4, WdfT, nullptr, t6T, 2048, 64, 256, 2048LL * 256, 0, 64LL * 2048, 0, 1, 64);
  mm(stream, adjb, t6T, bdf, out, 2048, 64, 2048, 0, 64LL * 2048, 2048LL * 64, 2, 2, 64);
}
#undef US

// Round 4
// 765.975 us; speedup vs baseline: 5.3224x; 1.0711x over previous
//
#include <hip/hip_runtime.h>
#include <math.h>

#define BATCH 8

typedef __attribute__((ext_vector_type(8))) short short8;
typedef __attribute__((ext_vector_type(4))) float f32x4;

__device__ __forceinline__ unsigned short f2b(float f) {
  union { float f; unsigned u; } v; v.f = f;
  unsigned r = v.u + 0x7fffu + ((v.u >> 16) & 1u);
  return (unsigned short)(r >> 16);
}
__device__ __forceinline__ float b2f(unsigned short h) {
  union { unsigned u; float f; } v; v.u = ((unsigned)h) << 16;
  return v.f;
}

__device__ __forceinline__ void gload16(const unsigned short* g, unsigned short* l) {
  __builtin_amdgcn_global_load_lds(
      (const __attribute__((address_space(1))) unsigned int*)g,
      (__attribute__((address_space(3))) unsigned int*)l, 16, 0, 0);
}

// LDS tile [rows][64] linear, XOR swizzle: cell (16B) index ^= (row&7).
__device__ __forceinline__ int lidx2(int r, int ko) {
  return r * 64 + ((((ko >> 3) ^ (r & 7)) << 3));
}

// ---------------- MFMA GEMM (all-direct staging) ----------------
// C = act(A@B + bias). A bf16 phys [M][K] ld=K. B bf16 phys [N][K] ld=K.
// OUT: 0 = bf16 [M][N], 1 = bf16 transposed [N][M], 2 = f32 [M][N].
template <int TN, int ACT, int OUT, bool HASBIAS>
__global__ __launch_bounds__(256) void mm_k(
    const unsigned short* __restrict__ A, const unsigned short* __restrict__ B,
    const float* __restrict__ bias, void* __restrict__ Cv,
    int M, int N, int K, long long sA, long long sB, long long sC) {
  constexpr int JF = TN / 32;
  __shared__ unsigned short As[128 * 64];
  __shared__ unsigned short Bs[TN * 64];

  const int b = blockIdx.z;
  A += (long long)b * sA;
  B += (long long)b * sB;
  const int m0 = blockIdx.y * 128, n0 = blockIdx.x * TN;
  const int t = threadIdx.x, lane = t & 63, w = t >> 6;
  const int wm = (w >> 1) * 64, wn = (w & 1) * (TN / 2);
  const int l15 = lane & 15, lg = lane >> 4;
  const int lrow = lane >> 3;
  const int gcell = (((lane & 7) ^ lrow) << 3);

  f32x4 acc[4][JF];
#pragma unroll
  for (int i = 0; i < 4; ++i)
#pragma unroll
    for (int j = 0; j < JF; ++j) acc[i][j] = (f32x4){0.f, 0.f, 0.f, 0.f};

  for (int k0 = 0; k0 < K; k0 += 64) {
#pragma unroll
    for (int i = 0; i < 4; ++i) {
      const int g = w * 4 + i;
      gload16(A + (long long)(m0 + g * 8 + lrow) * K + k0 + gcell, &As[g * 512]);
    }
#pragma unroll
    for (int i = 0; i < TN / 32; ++i) {
      const int g = w * (TN / 32) + i;
      gload16(B + (long long)(n0 + g * 8 + lrow) * K + k0 + gcell, &Bs[g * 512]);
    }
    __syncthreads();

#pragma unroll
    for (int kk = 0; kk < 2; ++kk) {
      const int ko = kk * 32 + lg * 8;
      short8 af[4], bf[JF];
#pragma unroll
      for (int i = 0; i < 4; ++i)
        af[i] = *(const short8*)&As[lidx2(wm + i * 16 + l15, ko)];
#pragma unroll
      for (int j = 0; j < JF; ++j)
        bf[j] = *(const short8*)&Bs[lidx2(wn + j * 16 + l15, ko)];
#pragma unroll
      for (int i = 0; i < 4; ++i)
#pragma unroll
        for (int j = 0; j < JF; ++j)
          acc[i][j] = __builtin_amdgcn_mfma_f32_16x16x32_bf16(af[i], bf[j],
                                                              acc[i][j], 0, 0, 0);
    }
    __syncthreads();
  }

  const long long cb = (long long)b * sC;
#pragma unroll
  for (int fj = 0; fj < JF; ++fj) {
    const int col = n0 + wn + fj * 16 + l15;
    const float bsv = HASBIAS ? bias[col] : 0.0f;
#pragma unroll
    for (int fi = 0; fi < 4; ++fi) {
      const int row0 = m0 + wm + fi * 16 + lg * 4;
      if (OUT == 1) {
        unsigned short pv[4];
#pragma unroll
        for (int e = 0; e < 4; ++e) {
          float v = acc[fi][fj][e] + bsv;
          if (ACT == 1) v = fmaxf(v, 0.0f);
          if (ACT == 2) v = (v > 20.0f) ? v : log1pf(expf(v));
          pv[e] = f2b(v);
        }
        ushort4 pk; pk.x = pv[0]; pk.y = pv[1]; pk.z = pv[2]; pk.w = pv[3];
        *(ushort4*)&((unsigned short*)Cv)[cb + (long long)col * M + row0] = pk;
      } else {
#pragma unroll
        for (int e = 0; e < 4; ++e) {
          float v = acc[fi][fj][e] + bsv;
          if (ACT == 1) v = fmaxf(v, 0.0f);
          if (ACT == 2) v = (v > 20.0f) ? v : log1pf(expf(v));
          const long long o = cb + (long long)(row0 + e) * N + col;
          if (OUT == 2) ((float*)Cv)[o] = v;
          else ((unsigned short*)Cv)[o] = f2b(v);
        }
      }
    }
  }
}

// ---------------- split column softmax over R of x [B][R][C] ----------------
// partial: each block = one (row-chunk, batch); thread covers 8 cols x RPT rows.
template <int RPT>
__global__ __launch_bounds__(256) void sm_partial_k(
    const unsigned short* __restrict__ x, float* __restrict__ pm,
    float* __restrict__ ps, int R, int C, long long sB, int NS) {
  const int b = blockIdx.y, blk = blockIdx.x;
  const int cpr = C >> 3;
  const int t = threadIdx.x;
  const int cslot = t & (cpr - 1);
  const int rsub = t / cpr;
  const int nsub = 256 / cpr;
  const int rowsPerBlock = R / NS;
  const int r0 = blk * rowsPerBlock + rsub * RPT;
  const unsigned short* p = x + (long long)b * sB + (long long)r0 * C + cslot * 8;
  union { uint4 v; unsigned short s[8]; } buf[RPT];
#pragma unroll
  for (int i = 0; i < RPT; ++i) buf[i].v = *(const uint4*)(p + (long long)i * C);
  float M[8], S[8];
#pragma unroll
  for (int j = 0; j < 8; ++j) M[j] = b2f(buf[0].s[j]);
#pragma unroll
  for (int i = 1; i < RPT; ++i)
#pragma unroll
    for (int j = 0; j < 8; ++j) M[j] = fmaxf(M[j], b2f(buf[i].s[j]));
#pragma unroll
  for (int j = 0; j < 8; ++j) S[j] = 0.f;
#pragma unroll
  for (int i = 0; i < RPT; ++i)
#pragma unroll
    for (int j = 0; j < 8; ++j) S[j] += __expf(b2f(buf[i].s[j]) - M[j]);
  const long long pi = (long long)(b * NS + blk) * nsub + rsub;
  float* pmo = pm + pi * C + cslot * 8;
  float* pso = ps + pi * C + cslot * 8;
  *(float4*)pmo = make_float4(M[0], M[1], M[2], M[3]);
  *(float4*)(pmo + 4) = make_float4(M[4], M[5], M[6], M[7]);
  *(float4*)pso = make_float4(S[0], S[1], S[2], S[3]);
  *(float4*)(pso + 4) = make_float4(S[4], S[5], S[6], S[7]);
}

__global__ __launch_bounds__(256) void sm_combine_k(
    const float* __restrict__ pm, const float* __restrict__ ps,
    float* __restrict__ Mf, float* __restrict__ Sinv, int C, int NP) {
  const int b = blockIdx.x, t = threadIdx.x;
  const int cpr = C >> 3;
  if (t >= cpr) return;
  const int c = t * 8;
  const float* pmB = pm + (long long)b * NP * C + c;
  const float* psB = ps + (long long)b * NP * C + c;
  float M[8], S[8];
#pragma unroll
  for (int j = 0; j < 8; ++j) { M[j] = pmB[j]; S[j] = psB[j]; }
  for (int e = 1; e < NP; ++e) {
    const float* pme = pmB + (long long)e * C;
    const float* pse = psB + (long long)e * C;
#pragma unroll
    for (int j = 0; j < 8; ++j) {
      const float m2 = pme[j], s2 = pse[j];
      const float nm = fmaxf(M[j], m2);
      S[j] = S[j] * __expf(M[j] - nm) + s2 * __expf(m2 - nm);
      M[j] = nm;
    }
  }
#pragma unroll
  for (int j = 0; j < 8; ++j) {
    Mf[(long long)b * C + c + j] = M[j];
    Sinv[(long long)b * C + c + j] = 1.0f / S[j];
  }
}

template <int RPT>
__global__ __launch_bounds__(256) void sm_norm_k(
    unsigned short* __restrict__ x, const float* __restrict__ Mf,
    const float* __restrict__ Sinv, int R, int C, long long sB, int NS) {
  const int b = blockIdx.y, blk = blockIdx.x;
  const int cpr = C >> 3;
  const int t = threadIdx.x;
  const int cslot = t & (cpr - 1);
  const int rsub = t / cpr;
  const int rowsPerBlock = R / NS;
  const int r0 = blk * rowsPerBlock + rsub * RPT;
  unsigned short* p = x + (long long)b * sB + (long long)r0 * C + cslot * 8;
  float M[8], Si[8];
#pragma unroll
  for (int j = 0; j < 8; ++j) {
    M[j] = Mf[(long long)b * C + cslot * 8 + j];
    Si[j] = Sinv[(long long)b * C + cslot * 8 + j];
  }
#pragma unroll
  for (int i = 0; i < RPT; ++i) {
    union { uint4 v; unsigned short s[8]; } buf;
    buf.v = *(const uint4*)(p + (long long)i * C);
#pragma unroll
    for (int j = 0; j < 8; ++j)
      buf.s[j] = f2b(__expf(b2f(buf.s[j]) - M[j]) * Si[j]);
    *(uint4*)(p + (long long)i * C) = buf.v;
  }
}

// ---------------- transpose (+optional f32->bf16): [B][R][C] -> [B][C][R] ----
template <bool F32IN>
__global__ __launch_bounds__(256) void trans_k(const void* __restrict__ srcv,
                                               unsigned short* __restrict__ dst,
                                               int R, int C, long long sIn,
                                               long long sOut) {
  __shared__ unsigned short L[64][65];
  const int b = blockIdx.z;
  const int r0 = blockIdx.y * 64, c0 = blockIdx.x * 64;
  const int t = threadIdx.x;
  const int lr = t >> 4, lc = (t & 15) * 4;
#pragma unroll
  for (int i = 0; i < 4; ++i) {
    const int rr = r0 + lr + 16 * i;
    if (F32IN) {
      const float* s = (const float*)srcv + (long long)b * sIn;
      const float4 v = *(const float4*)&s[(long long)rr * C + c0 + lc];
      L[lr + 16 * i][lc + 0] = f2b(v.x);
      L[lr + 16 * i][lc + 1] = f2b(v.y);
      L[lr + 16 * i][lc + 2] = f2b(v.z);
      L[lr + 16 * i][lc + 3] = f2b(v.w);
    } else {
      const unsigned short* s = (const unsigned short*)srcv + (long long)b * sIn;
      const ushort4 v = *(const ushort4*)&s[(long long)rr * C + c0 + lc];
      L[lr + 16 * i][lc + 0] = v.x;
      L[lr + 16 * i][lc + 1] = v.y;
      L[lr + 16 * i][lc + 2] = v.z;
      L[lr + 16 * i][lc + 3] = v.w;
    }
  }
  __syncthreads();
#pragma unroll
  for (int i = 0; i < 4; ++i) {
    ushort4 o;
    o.x = L[lc + 0][lr + 16 * i];
    o.y = L[lc + 1][lr + 16 * i];
    o.z = L[lc + 2][lr + 16 * i];
    o.w = L[lc + 3][lr + 16 * i];
    *(ushort4*)&dst[(long long)b * sOut + (long long)(c0 + lr + 16 * i) * R + r0 + lc] = o;
  }
}

// ---------------- fused weight transposes (one launch) ----------------
struct WT { const float* src; unsigned short* dst; int R, C, tileOff; };
struct WTab { WT e[11]; };

__global__ __launch_bounds__(256) void wtrans_k(WTab tab) {
  __shared__ unsigned short L[64][65];
  const int tile = blockIdx.x;
  int i = 0;
#pragma unroll
  for (int j = 1; j < 11; ++j)
    if (tab.e[j].tileOff <= tile) i = j;
  const WT w = tab.e[i];
  const int lt = tile - w.tileOff;
  const int tc = w.C / 64;
  const int r0 = (lt / tc) * 64, c0 = (lt % tc) * 64;
  const int t = threadIdx.x;
  const int lr = t >> 4, lc = (t & 15) * 4;
#pragma unroll
  for (int k = 0; k < 4; ++k) {
    const int rr = r0 + lr + 16 * k;
    const float4 v = *(const float4*)&w.src[(long long)rr * w.C + c0 + lc];
    L[lr + 16 * k][lc + 0] = f2b(v.x);
    L[lr + 16 * k][lc + 1] = f2b(v.y);
    L[lr + 16 * k][lc + 2] = f2b(v.z);
    L[lr + 16 * k][lc + 3] = f2b(v.w);
  }
  __syncthreads();
#pragma unroll
  for (int k = 0; k < 4; ++k) {
    ushort4 o;
    o.x = L[lc + 0][lr + 16 * k];
    o.y = L[lc + 1][lr + 16 * k];
    o.z = L[lc + 2][lr + 16 * k];
    o.w = L[lc + 3][lr + 16 * k];
    *(ushort4*)&w.dst[(long long)(c0 + lr + 16 * k) * w.R + r0 + lc] = o;
  }
}

// ---------------- f32 -> bf16 ----------------
__global__ __launch_bounds__(256) void f2b_k(const float* __restrict__ s,
                                             unsigned short* __restrict__ d, int n4) {
  const int i = blockIdx.x * 256 + threadIdx.x;
  if (i < n4) {
    const float4 v = ((const float4*)s)[i];
    ushort4 o;
    o.x = f2b(v.x); o.y = f2b(v.y); o.z = f2b(v.z); o.w = f2b(v.w);
    ((ushort4*)d)[i] = o;
  }
}

// ---------------- reparameterize ----------------
__global__ __launch_bounds__(256) void reparam_k(
    const float* __restrict__ h3, const float* __restrict__ eps,
    float* __restrict__ om, float* __restrict__ olv,
    unsigned short* __restrict__ z, int total) {
  const int i = blockIdx.x * 256 + threadIdx.x;
  if (i >= total) return;
  const int j = i & 63;
  const long long r = i >> 6;
  const float m = h3[r * 128 + j];
  const float lv = h3[r * 128 + 64 + j];
  om[i] = m;
  olv[i] = lv;
  z[i] = f2b(m + expf(0.5f * lv) * eps[i]);
}

// ---------------- host dispatch ----------------
static void mm(hipStream_t st, const unsigned short* A, const unsigned short* B,
               const float* bias, void* C, int M, int N, int K, long long sA,
               long long sB, long long sC, int act, int outmode, int tn) {
  dim3 g(N / tn, M / 128, BATCH), blk(256);
  if (tn == 64) {
    if (outmode == 0)
      mm_k<64, 0, 0, false><<<g, blk, 0, st>>>(A, B, nullptr, C, M, N, K, sA, sB, sC);
    else if (outmode == 1)
      mm_k<64, 0, 1, false><<<g, blk, 0, st>>>(A, B, nullptr, C, M, N, K, sA, sB, sC);
    else
      mm_k<64, 2, 2, true><<<g, blk, 0, st>>>(A, B, bias, C, M, N, K, sA, sB, sC);
  } else if (outmode == 0) {
    if (act == 1)
      mm_k<128, 1, 0, true><<<g, blk, 0, st>>>(A, B, bias, C, M, N, K, sA, sB, sC);
    else
      mm_k<128, 0, 0, false><<<g, blk, 0, st>>>(A, B, nullptr, C, M, N, K, sA, sB, sC);
  } else if (outmode == 1) {
    if (act == 1)
      mm_k<128, 1, 1, true><<<g, blk, 0, st>>>(A, B, bias, C, M, N, K, sA, sB, sC);
    else
      mm_k<128, 0, 1, false><<<g, blk, 0, st>>>(A, B, nullptr, C, M, N, K, sA, sB, sC);
  } else {
    mm_k<128, 0, 2, true><<<g, blk, 0, st>>>(A, B, bias, C, M, N, K, sA, sB, sC);
  }
}

extern "C" void kernel_launch(void* const* d_in, const int* in_sizes, int n_in,
                              void* d_out, int out_size, void* d_ws, size_t ws_size,
                              hipStream_t stream) {
  const float* x      = (const float*)d_in[0];
  const float* eps    = (const float*)d_in[1];
  const float* adj    = (const float*)d_in[2];
  const float* We1    = (const float*)d_in[3];
  const float* be1    = (const float*)d_in[4];
  const float* Kemb1  = (const float*)d_in[5];
  const float* Kpool1 = (const float*)d_in[6];
  const float* We2    = (const float*)d_in[7];
  const float* be2    = (const float*)d_in[8];
  const float* Kemb2  = (const float*)d_in[9];
  const float* Kpool2 = (const float*)d_in[10];
  const float* We3    = (const float*)d_in[11];
  const float* be3    = (const float*)d_in[12];
  const float* Wd0    = (const float*)d_in[13];
  const float* bd0    = (const float*)d_in[14];
  const float* Wd1    = (const float*)d_in[15];
  const float* bd1    = (const float*)d_in[16];
  const float* Wd2    = (const float*)d_in[17];
  const float* bd2    = (const float*)d_in[18];
  const float* Wdf    = (const float*)d_in[19];
  const float* bdf    = (const float*)d_in[20];
  (void)in_sizes; (void)n_in; (void)ws_size; (void)out_size;

  float* out = (float*)d_out;
  float* out_mean = out + (long long)8 * 2048 * 64;
  float* out_lv = out_mean + (long long)8 * 512 * 64;

  char* base = (char*)d_ws;
  size_t off = 0;
  auto alloc = [&](size_t bytes) {
    char* p = base + off;
    off += (bytes + 255) & ~(size_t)255;
    return p;
  };
#define US unsigned short
  US* adjb  = (US*)alloc(2048LL * 2048 * 2);
  US* xT    = (US*)alloc(8LL * 64 * 2048 * 2);
  US* Y0    = (US*)alloc(8LL * 2048 * 64 * 2);
  US* h1T   = (US*)alloc(8LL * 256 * 2048 * 2);
  US* g1    = (US*)alloc(8LL * 2048 * 256 * 2);
  US* z1s1  = (US*)alloc(8LL * 1280 * 2048 * 2);  // rows 0-255 z1T, 256-1279 s1T
  US* AS1   = (US*)alloc(8LL * 2048 * 1024 * 2);
  US* AS1T  = (US*)alloc(8LL * 1024 * 2048 * 2);
  US* A1    = (US*)alloc(8LL * 1024 * 1024 * 2);
  US* xp1   = (US*)alloc(8LL * 1024 * 256 * 2);
  US* t1T   = (US*)alloc(8LL * 256 * 1024 * 2);
  US* h2T   = (US*)alloc(8LL * 256 * 1024 * 2);
  US* g2    = (US*)alloc(8LL * 1024 * 256 * 2);
  US* z2s2  = (US*)alloc(8LL * 768 * 1024 * 2);   // rows 0-255 z2T, 256-767 s2T
  US* AS2   = (US*)alloc(8LL * 1024 * 512 * 2);
  US* AS2T  = (US*)alloc(8LL * 512 * 1024 * 2);
  US* A2    = (US*)alloc(8LL * 512 * 512 * 2);
  US* xp2   = (US*)alloc(8LL * 512 * 256 * 2);
  US* t2T   = (US*)alloc(8LL * 128 * 512 * 2);
  float* h3f = (float*)alloc(8LL * 512 * 128 * 4);
  US* zlb   = (US*)alloc(8LL * 512 * 64 * 2);
  US* t3T   = (US*)alloc(8LL * 256 * 512 * 2);
  US* d0    = (US*)alloc(8LL * 512 * 256 * 2);
  US* t4T   = (US*)alloc(8LL * 256 * 512 * 2);
  US* d2    = (US*)alloc(8LL * 1024 * 256 * 2);
  US* t5T   = (US*)alloc(8LL * 256 * 1024 * 2);
  US* d4    = (US*)alloc(8LL * 2048 * 256 * 2);
  US* t6T   = (US*)alloc(8LL * 64 * 2048 * 2);
  float* pm   = (float*)alloc(8LL * 128 * 2048 * 4);
  float* ps   = (float*)alloc(8LL * 128 * 2048 * 4);
  float* Mf   = (float*)alloc(8LL * 2048 * 4);
  float* Sinv = (float*)alloc(8LL * 2048 * 4);
  US* We1T  = (US*)alloc(256 * 64 * 2);
  US* KeKp1 = (US*)alloc(1280 * 256 * 2);
  US* We2T  = (US*)alloc(256 * 256 * 2);
  US* KeKp2 = (US*)alloc(768 * 256 * 2);
  US* We3T  = (US*)alloc(128 * 256 * 2);
  US* Wd0T  = (US*)alloc(256 * 64 * 2);
  US* Wd1T  = (US*)alloc(256 * 256 * 2);
  US* Wd2T  = (US*)alloc(256 * 256 * 2);
  US* WdfT  = (US*)alloc(64 * 256 * 2);

  // ---- input conversions ----
  f2b_k<<<dim3(2048 * 2048 / 4 / 256), dim3(256), 0, stream>>>(adj, adjb, 2048 * 2048 / 4);
  trans_k<true><<<dim3(1, 32, 8), dim3(256), 0, stream>>>(x, xT, 2048, 64,
                                                          2048LL * 64, 64LL * 2048);
  {
    WTab tab;
    int toff = 0, i = 0;
    auto add = [&](const float* s, US* d, int R, int C) {
      tab.e[i++] = WT{s, d, R, C, toff};
      toff += (R / 64) * (C / 64);
    };
    add(We1, We1T, 64, 256);
    add(Kemb1, KeKp1, 256, 256);
    add(Kpool1, KeKp1 + 256 * 256, 256, 1024);
    add(We2, We2T, 256, 256);
    add(Kemb2, KeKp2, 256, 256);
    add(Kpool2, KeKp2 + 256 * 256, 256, 512);
    add(We3, We3T, 256, 128);
    add(Wd0, Wd0T, 64, 256);
    add(Wd1, Wd1T, 256, 256);
    add(Wd2, Wd2T, 256, 256);
    add(Wdf, WdfT, 256, 64);
    wtrans_k<<<dim3(toff), dim3(256), 0, stream>>>(tab);
  }

  US* z1T = z1s1;
  US* s1T = z1s1 + 256 * 2048;
  US* z2T = z2s2;
  US* s2T = z2s2 + 256 * 1024;
  const long long Sz1 = 1280LL * 2048, Sz2 = 768LL * 1024;
  const long long SY0 = 2048LL * 64, Sh1T = 256LL * 2048, Sg1 = 2048LL * 256;
  const long long SAS1 = 2048LL * 1024, SA1 = 1024LL * 1024;

  // ---------------- encode ----------------
  mm(stream, adjb, xT, nullptr, Y0, 2048, 64, 2048, 0, 64LL * 2048, SY0, 0, 0, 64);
  mm(stream, Y0, We1T, be1, h1T, 2048, 256, 64, SY0, 0, Sh1T, 1, 1, 128);
  mm(stream, adjb, h1T, nullptr, g1, 2048, 256, 2048, 0, Sh1T, Sg1, 0, 0, 128);
  mm(stream, g1, KeKp1, nullptr, z1s1, 2048, 1280, 256, Sg1, 0, Sz1, 0, 1, 128);
  // softmax over rows of s1T [1024][2048] per batch
  sm_partial_k<8><<<dim3(128, 8), dim3(256), 0, stream>>>(s1T, pm, ps, 1024, 2048, Sz1, 128);
  sm_combine_k<<<dim3(8), dim3(256), 0, stream>>>(pm, ps, Mf, Sinv, 2048, 128);
  sm_norm_k<8><<<dim3(128, 8), dim3(256), 0, stream>>>(s1T, Mf, Sinv, 1024, 2048, Sz1, 128);
  mm(stream, adjb, s1T, nullptr, AS1, 2048, 1024, 2048, 0, Sz1, SAS1, 0, 0, 128);
  trans_k<false><<<dim3(16, 32, 8), dim3(256), 0, stream>>>(AS1, AS1T, 2048, 1024,
                                                            SAS1, 1024LL * 2048);
  mm(stream, s1T, AS1T, nullptr, A1, 1024, 1024, 2048, Sz1, 1024LL * 2048, SA1, 0, 0, 128);
  mm(stream, s1T, z1T, nullptr, xp1, 1024, 256, 2048, Sz1, Sz1, 1024LL * 256, 0, 0, 128);
  mm(stream, xp1, We2T, nullptr, t1T, 1024, 256, 256, 1024LL * 256, 0, 256LL * 1024, 0, 1, 128);
  mm(stream, A1, t1T, be2, h2T, 1024, 256, 1024, SA1, 256LL * 1024, 256LL * 1024, 1, 1, 128);
  mm(stream, A1, h2T, nullptr, g2, 1024, 256, 1024, SA1, 256LL * 1024, 1024LL * 256, 0, 0, 128);
  mm(stream, g2, KeKp2, nullptr, z2s2, 1024, 768, 256, 1024LL * 256, 0, Sz2, 0, 1, 128);
  // softmax over rows of s2T [512][1024] per batch
  sm_partial_k<4><<<dim3(64, 8), dim3(256), 0, stream>>>(s2T, pm, ps, 512, 1024, Sz2, 64);
  sm_combine_k<<<dim3(8), dim3(256), 0, stream>>>(pm, ps, Mf, Sinv, 1024, 128);
  sm_norm_k<4><<<dim3(64, 8), dim3(256), 0, stream>>>(s2T, Mf, Sinv, 512, 1024, Sz2, 64);
  mm(stream, A1, s2T, nullptr, AS2, 1024, 512, 1024, SA1, Sz2, 1024LL * 512, 0, 0, 128);
  trans_k<false><<<dim3(8, 16, 8), dim3(256), 0, stream>>>(AS2, AS2T, 1024, 512,
                                                           1024LL * 512, 512LL * 1024);
  mm(stream, s2T, AS2T, nullptr, A2, 512, 512, 1024, Sz2, 512LL * 1024, 512LL * 512, 0, 0, 128);
  mm(stream, s2T, z2T, nullptr, xp2, 512, 256, 1024, Sz2, Sz2, 512LL * 256, 0, 0, 128);
  mm(stream, xp2, We3T, nullptr, t2T, 512, 128, 256, 512LL * 256, 0, 128LL * 512, 0, 1, 128);
  mm(stream, A2, t2T, be3, h3f, 512, 128, 512, 512LL * 512, 128LL * 512, 512LL * 128, 0, 2, 128);
  reparam_k<<<dim3(8 * 512 * 64 / 256), dim3(256), 0, stream>>>(h3f, eps, out_mean,
                                                                out_lv, zlb, 8 * 512 * 64);

  // ---------------- decode ----------------
  mm(stream, zlb, Wd0T, nullptr, t3T, 512, 256, 64, 512LL * 64, 0, 256LL * 512, 0, 1, 128);
  mm(stream, A2, t3T, bd0, d0, 512, 256, 512, 512LL * 512, 256LL * 512, 512LL * 256, 1, 0, 128);
  mm(stream, d0, Wd1T, nullptr, t4T, 512, 256, 256, 512LL * 256, 0, 256LL * 512, 0, 1, 128);
  mm(stream, AS2, t4T, bd1, d2, 1024, 256, 512, 1024LL * 512, 256LL * 512, 1024LL * 256, 1, 0, 128);
  mm(stream, d2, Wd2T, nullptr, t5T, 1024, 256, 256, 1024LL * 256, 0, 256LL * 1024, 0, 1, 128);
  mm(stream, AS1, t5T, bd2, d4, 2048, 256, 1024, SAS1, 256LL * 1024, 2048LL * 256, 1, 0, 128);
  mm(stream, d4, WdfT, nullptr, t6T, 2048, 64, 256, 2048LL * 256, 0, 64LL * 2048, 0, 1, 64);
  mm(stream, adjb, t6T, bdf, out, 2048, 64, 2048, 0, 64LL * 2048, 2048LL * 64, 2, 2, 64);
#undef US
}

// Round 5
// 733.518 us; speedup vs baseline: 5.5579x; 1.0442x over previous
//
#include <hip/hip_runtime.h>
#include <math.h>

#define BATCH 8
typedef unsigned short US;

typedef __attribute__((ext_vector_type(8))) short short8;
typedef __attribute__((ext_vector_type(4))) float f32x4;

__device__ __forceinline__ US f2b(float f) {
  union { float f; unsigned u; } v; v.f = f;
  unsigned r = v.u + 0x7fffu + ((v.u >> 16) & 1u);
  return (US)(r >> 16);
}
__device__ __forceinline__ float b2f(US h) {
  union { unsigned u; float f; } v; v.u = ((unsigned)h) << 16;
  return v.f;
}

__device__ __forceinline__ void gload16(const US* g, US* l) {
  __builtin_amdgcn_global_load_lds(
      (const __attribute__((address_space(1))) unsigned int*)g,
      (__attribute__((address_space(3))) unsigned int*)l, 16, 0, 0);
}

// LDS tile [rows][64] linear, XOR swizzle: 16B-cell index ^= (row&7).
__device__ __forceinline__ int lidx2(int r, int ko) {
  return r * 64 + ((((ko >> 3) ^ (r & 7)) << 3));
}

// ---------------- MFMA GEMM ----------------
// C = act(A@B + bias). A bf16 phys [M][lda] (reads cols k0..), B bf16 phys [N][K].
// OUT: 0=bf16 [M][N], 1=bf16 [N][M] (transposed), 2=f32 [M][N],
//      3=dual: bf16 [M][N] to Cv AND bf16 [N][M] to Cv2.
template <int TN, int ACT, int OUT, bool HASBIAS>
__global__ __launch_bounds__(256) void mm_k(
    const US* __restrict__ A, const US* __restrict__ B,
    const float* __restrict__ bias, void* __restrict__ Cv, void* __restrict__ Cv2,
    int M, int N, int K, int lda, long long sA, long long sB, long long sC,
    long long sC2, int gx, int gy) {
  constexpr int JF = TN / 32;
  __shared__ US As[128 * 64];
  __shared__ US Bs[TN * 64];

  // XCD-chunked bijective swizzle: xcd = bid%8 owns a contiguous logical chunk
  // (= exactly one batch, since chunk == gx*gy and z is slowest).
  const int nb = blockIdx.x;
  const int nb2 = (nb & 7) * (gx * gy) + (nb >> 3);
  const int bx = nb2 % gx;
  const int by = (nb2 / gx) % gy;
  const int b = nb2 / (gx * gy);

  A += (long long)b * sA;
  B += (long long)b * sB;
  const int m0 = by * 128, n0 = bx * TN;
  const int t = threadIdx.x, lane = t & 63, w = t >> 6;
  const int wm = (w >> 1) * 64, wn = (w & 1) * (TN / 2);
  const int l15 = lane & 15, lg = lane >> 4;
  const int lrow = lane >> 3;
  const int gcell = (((lane & 7) ^ lrow) << 3);  // pre-swizzled source cell

  f32x4 acc[4][JF];
#pragma unroll
  for (int i = 0; i < 4; ++i)
#pragma unroll
    for (int j = 0; j < JF; ++j) acc[i][j] = (f32x4){0.f, 0.f, 0.f, 0.f};

  for (int k0 = 0; k0 < K; k0 += 64) {
#pragma unroll
    for (int i = 0; i < 4; ++i) {
      const int g = w * 4 + i;
      gload16(A + (long long)(m0 + g * 8 + lrow) * lda + k0 + gcell, &As[g * 512]);
    }
#pragma unroll
    for (int i = 0; i < TN / 32; ++i) {
      const int g = w * (TN / 32) + i;
      gload16(B + (long long)(n0 + g * 8 + lrow) * K + k0 + gcell, &Bs[g * 512]);
    }
    __syncthreads();

#pragma unroll
    for (int kk = 0; kk < 2; ++kk) {
      const int ko = kk * 32 + lg * 8;
      short8 af[4], bf[JF];
#pragma unroll
      for (int i = 0; i < 4; ++i)
        af[i] = *(const short8*)&As[lidx2(wm + i * 16 + l15, ko)];
#pragma unroll
      for (int j = 0; j < JF; ++j)
        bf[j] = *(const short8*)&Bs[lidx2(wn + j * 16 + l15, ko)];
#pragma unroll
      for (int i = 0; i < 4; ++i)
#pragma unroll
        for (int j = 0; j < JF; ++j)
          acc[i][j] = __builtin_amdgcn_mfma_f32_16x16x32_bf16(af[i], bf[j],
                                                              acc[i][j], 0, 0, 0);
    }
    __syncthreads();
  }

  const long long cb = (long long)b * sC;
  const long long cb2 = (long long)b * sC2;
#pragma unroll
  for (int fj = 0; fj < JF; ++fj) {
    const int col = n0 + wn + fj * 16 + l15;
    const float bsv = HASBIAS ? bias[col] : 0.0f;
#pragma unroll
    for (int fi = 0; fi < 4; ++fi) {
      const int row0 = m0 + wm + fi * 16 + lg * 4;
      float v[4];
#pragma unroll
      for (int e = 0; e < 4; ++e) {
        float x = acc[fi][fj][e] + bsv;
        if (ACT == 1) x = fmaxf(x, 0.0f);
        if (ACT == 2) x = (x > 20.0f) ? x : log1pf(expf(x));
        v[e] = x;
      }
      if (OUT == 1 || OUT == 3) {
        ushort4 pk;
        pk.x = f2b(v[0]); pk.y = f2b(v[1]); pk.z = f2b(v[2]); pk.w = f2b(v[3]);
        US* c2 = (OUT == 3) ? (US*)Cv2 : (US*)Cv;
        *(ushort4*)&c2[cb2 + (long long)col * M + row0] = pk;
      }
      if (OUT == 0 || OUT == 3) {
#pragma unroll
        for (int e = 0; e < 4; ++e)
          ((US*)Cv)[cb + (long long)(row0 + e) * N + col] = f2b(v[e]);
      }
      if (OUT == 2) {
#pragma unroll
        for (int e = 0; e < 4; ++e)
          ((float*)Cv)[cb + (long long)(row0 + e) * N + col] = v[e];
      }
    }
  }
}

// ---------------- split column softmax over R of x [B][R][C] ----------------
template <int RPT>
__global__ __launch_bounds__(256) void sm_partial_k(
    const US* __restrict__ x, float* __restrict__ pm, float* __restrict__ ps,
    int R, int C, long long sB, int NS) {
  const int b = blockIdx.y, blk = blockIdx.x;
  const int cpr = C >> 3;
  const int t = threadIdx.x;
  const int cslot = t & (cpr - 1);
  const int rsub = t / cpr;
  const int nsub = 256 / cpr;
  const int rowsPerBlock = R / NS;
  const int r0 = blk * rowsPerBlock + rsub * RPT;
  const US* p = x + (long long)b * sB + (long long)r0 * C + cslot * 8;
  union { uint4 v; US s[8]; } buf[RPT];
#pragma unroll
  for (int i = 0; i < RPT; ++i) buf[i].v = *(const uint4*)(p + (long long)i * C);
  float M[8], S[8];
#pragma unroll
  for (int j = 0; j < 8; ++j) M[j] = b2f(buf[0].s[j]);
#pragma unroll
  for (int i = 1; i < RPT; ++i)
#pragma unroll
    for (int j = 0; j < 8; ++j) M[j] = fmaxf(M[j], b2f(buf[i].s[j]));
#pragma unroll
  for (int j = 0; j < 8; ++j) S[j] = 0.f;
#pragma unroll
  for (int i = 0; i < RPT; ++i)
#pragma unroll
    for (int j = 0; j < 8; ++j) S[j] += __expf(b2f(buf[i].s[j]) - M[j]);
  const long long pi = (long long)(b * NS + blk) * nsub + rsub;
  float* pmo = pm + pi * C + cslot * 8;
  float* pso = ps + pi * C + cslot * 8;
  *(float4*)pmo = make_float4(M[0], M[1], M[2], M[3]);
  *(float4*)(pmo + 4) = make_float4(M[4], M[5], M[6], M[7]);
  *(float4*)pso = make_float4(S[0], S[1], S[2], S[3]);
  *(float4*)(pso + 4) = make_float4(S[4], S[5], S[6], S[7]);
}

__global__ __launch_bounds__(256) void sm_combine_k(
    const float* __restrict__ pm, const float* __restrict__ ps,
    float* __restrict__ Mf, float* __restrict__ Sinv, int C, int NP) {
  const int b = blockIdx.x, t = threadIdx.x;
  const int cpr = C >> 3;
  if (t >= cpr) return;
  const int c = t * 8;
  const float* pmB = pm + (long long)b * NP * C + c;
  const float* psB = ps + (long long)b * NP * C + c;
  float M[8], S[8];
#pragma unroll
  for (int j = 0; j < 8; ++j) { M[j] = pmB[j]; S[j] = psB[j]; }
  for (int e = 1; e < NP; ++e) {
    const float* pme = pmB + (long long)e * C;
    const float* pse = psB + (long long)e * C;
#pragma unroll
    for (int j = 0; j < 8; ++j) {
      const float m2 = pme[j], s2 = pse[j];
      const float nm = fmaxf(M[j], m2);
      S[j] = S[j] * __expf(M[j] - nm) + s2 * __expf(m2 - nm);
      M[j] = nm;
    }
  }
#pragma unroll
  for (int j = 0; j < 8; ++j) {
    Mf[(long long)b * C + c + j] = M[j];
    Sinv[(long long)b * C + c + j] = 1.0f / S[j];
  }
}

template <int RPT>
__global__ __launch_bounds__(256) void sm_norm_k(
    US* __restrict__ x, const float* __restrict__ Mf,
    const float* __restrict__ Sinv, int R, int C, long long sB, int NS) {
  const int b = blockIdx.y, blk = blockIdx.x;
  const int cpr = C >> 3;
  const int t = threadIdx.x;
  const int cslot = t & (cpr - 1);
  const int rsub = t / cpr;
  const int rowsPerBlock = R / NS;
  const int r0 = blk * rowsPerBlock + rsub * RPT;
  US* p = x + (long long)b * sB + (long long)r0 * C + cslot * 8;
  float M[8], Si[8];
#pragma unroll
  for (int j = 0; j < 8; ++j) {
    M[j] = Mf[(long long)b * C + cslot * 8 + j];
    Si[j] = Sinv[(long long)b * C + cslot * 8 + j];
  }
#pragma unroll
  for (int i = 0; i < RPT; ++i) {
    union { uint4 v; US s[8]; } buf;
    buf.v = *(const uint4*)(p + (long long)i * C);
#pragma unroll
    for (int j = 0; j < 8; ++j)
      buf.s[j] = f2b(__expf(b2f(buf.s[j]) - M[j]) * Si[j]);
    *(uint4*)(p + (long long)i * C) = buf.v;
  }
}

// ---------------- f32 transpose -> bf16: [B][R][C] -> [B][C][R] ----
__global__ __launch_bounds__(256) void trans_k(const float* __restrict__ src,
                                               US* __restrict__ dst, int R, int C,
                                               long long sIn, long long sOut) {
  __shared__ US L[64][65];
  const int b = blockIdx.z;
  const int r0 = blockIdx.y * 64, c0 = blockIdx.x * 64;
  const int t = threadIdx.x;
  const int lr = t >> 4, lc = (t & 15) * 4;
  const float* s = src + (long long)b * sIn;
#pragma unroll
  for (int i = 0; i < 4; ++i) {
    const int rr = r0 + lr + 16 * i;
    const float4 v = *(const float4*)&s[(long long)rr * C + c0 + lc];
    L[lr + 16 * i][lc + 0] = f2b(v.x);
    L[lr + 16 * i][lc + 1] = f2b(v.y);
    L[lr + 16 * i][lc + 2] = f2b(v.z);
    L[lr + 16 * i][lc + 3] = f2b(v.w);
  }
  __syncthreads();
#pragma unroll
  for (int i = 0; i < 4; ++i) {
    ushort4 o;
    o.x = L[lc + 0][lr + 16 * i];
    o.y = L[lc + 1][lr + 16 * i];
    o.z = L[lc + 2][lr + 16 * i];
    o.w = L[lc + 3][lr + 16 * i];
    *(ushort4*)&dst[(long long)b * sOut + (long long)(c0 + lr + 16 * i) * R + r0 + lc] = o;
  }
}

// ---------------- fused weight transposes ----------------
struct WT { const float* src; US* dst; int R, C, tileOff; };
struct WTab { WT e[11]; };

__global__ __launch_bounds__(256) void wtrans_k(WTab tab) {
  __shared__ US L[64][65];
  const int tile = blockIdx.x;
  int i = 0;
#pragma unroll
  for (int j = 1; j < 11; ++j)
    if (tab.e[j].tileOff <= tile) i = j;
  const WT w = tab.e[i];
  const int lt = tile - w.tileOff;
  const int tc = w.C / 64;
  const int r0 = (lt / tc) * 64, c0 = (lt % tc) * 64;
  const int t = threadIdx.x;
  const int lr = t >> 4, lc = (t & 15) * 4;
#pragma unroll
  for (int k = 0; k < 4; ++k) {
    const int rr = r0 + lr + 16 * k;
    const float4 v = *(const float4*)&w.src[(long long)rr * w.C + c0 + lc];
    L[lr + 16 * k][lc + 0] = f2b(v.x);
    L[lr + 16 * k][lc + 1] = f2b(v.y);
    L[lr + 16 * k][lc + 2] = f2b(v.z);
    L[lr + 16 * k][lc + 3] = f2b(v.w);
  }
  __syncthreads();
#pragma unroll
  for (int k = 0; k < 4; ++k) {
    ushort4 o;
    o.x = L[lc + 0][lr + 16 * k];
    o.y = L[lc + 1][lr + 16 * k];
    o.z = L[lc + 2][lr + 16 * k];
    o.w = L[lc + 3][lr + 16 * k];
    *(ushort4*)&w.dst[(long long)(c0 + lr + 16 * k) * w.R + r0 + lc] = o;
  }
}

// ---------------- f32 -> bf16 ----------------
__global__ __launch_bounds__(256) void f2b_k(const float* __restrict__ s,
                                             US* __restrict__ d, int n4) {
  const int i = blockIdx.x * 256 + threadIdx.x;
  if (i < n4) {
    const float4 v = ((const float4*)s)[i];
    ushort4 o;
    o.x = f2b(v.x); o.y = f2b(v.y); o.z = f2b(v.z); o.w = f2b(v.w);
    ((ushort4*)d)[i] = o;
  }
}

// ---------------- reparameterize ----------------
__global__ __launch_bounds__(256) void reparam_k(
    const float* __restrict__ h3, const float* __restrict__ eps,
    float* __restrict__ om, float* __restrict__ olv, US* __restrict__ z,
    int total) {
  const int i = blockIdx.x * 256 + threadIdx.x;
  if (i >= total) return;
  const int j = i & 63;
  const long long r = i >> 6;
  const float m = h3[r * 128 + j];
  const float lv = h3[r * 128 + 64 + j];
  om[i] = m;
  olv[i] = lv;
  z[i] = f2b(m + expf(0.5f * lv) * eps[i]);
}

// ---------------- host dispatch ----------------
static void mm(hipStream_t st, const US* A, const US* B, const float* bias,
               void* C, void* C2, int M, int N, int K, int lda, long long sA,
               long long sB, long long sC, long long sC2, int act, int outm,
               int tn) {
  const int gx = N / tn, gy = M / 128;
  dim3 g(gx * gy * BATCH), blk(256);
#define L(TN, ACT, OUT, HB) \
  mm_k<TN, ACT, OUT, HB><<<g, blk, 0, st>>>(A, B, bias, C, C2, M, N, K, lda, sA, sB, sC, sC2, gx, gy)
  if (tn == 64) {
    if (outm == 0) L(64, 0, 0, false);
    else if (outm == 1) L(64, 0, 1, false);
    else L(64, 2, 2, true);            // final output: softplus + bias, f32
  } else {
    if (outm == 0) {
      if (act == 1) L(128, 1, 0, true);
      else L(128, 0, 0, false);
    } else if (outm == 1) {
      if (act == 1) L(128, 1, 1, true);
      else L(128, 0, 1, false);
    } else if (outm == 2) L(128, 0, 2, true);
    else L(128, 0, 3, false);          // dual
  }
#undef L
}

extern "C" void kernel_launch(void* const* d_in, const int* in_sizes, int n_in,
                              void* d_out, int out_size, void* d_ws, size_t ws_size,
                              hipStream_t stream) {
  const float* x      = (const float*)d_in[0];
  const float* eps    = (const float*)d_in[1];
  const float* adj    = (const float*)d_in[2];
  const float* We1    = (const float*)d_in[3];
  const float* be1    = (const float*)d_in[4];
  const float* Kemb1  = (const float*)d_in[5];
  const float* Kpool1 = (const float*)d_in[6];
  const float* We2    = (const float*)d_in[7];
  const float* be2    = (const float*)d_in[8];
  const float* Kemb2  = (const float*)d_in[9];
  const float* Kpool2 = (const float*)d_in[10];
  const float* We3    = (const float*)d_in[11];
  const float* be3    = (const float*)d_in[12];
  const float* Wd0    = (const float*)d_in[13];
  const float* bd0    = (const float*)d_in[14];
  const float* Wd1    = (const float*)d_in[15];
  const float* bd1    = (const float*)d_in[16];
  const float* Wd2    = (const float*)d_in[17];
  const float* bd2    = (const float*)d_in[18];
  const float* Wdf    = (const float*)d_in[19];
  const float* bdf    = (const float*)d_in[20];
  (void)in_sizes; (void)n_in; (void)ws_size; (void)out_size;

  float* out = (float*)d_out;
  float* out_mean = out + (long long)8 * 2048 * 64;
  float* out_lv = out_mean + (long long)8 * 512 * 64;

  char* base = (char*)d_ws;
  size_t off = 0;
  auto alloc = [&](size_t bytes) {
    char* p = base + off;
    off += (bytes + 255) & ~(size_t)255;
    return p;
  };
  US* adjb = (US*)alloc(2048LL * 2048 * 2);
  US* xT   = (US*)alloc(8LL * 64 * 2048 * 2);
  US* Y0   = (US*)alloc(8LL * 2048 * 64 * 2);
  US* h1T  = (US*)alloc(8LL * 256 * 2048 * 2);
  US* g1   = (US*)alloc(8LL * 2048 * 256 * 2);
  // stage-1 region: per batch rows [s1T(1024) | z1T(256) | AS1T(1024)] x 2048
  US* R1   = (US*)alloc(8LL * 2304 * 2048 * 2);
  US* AS1  = (US*)alloc(8LL * 2048 * 1024 * 2);
  US* P1o  = (US*)alloc(8LL * 1024 * 1280 * 2);   // [xp1(256c) | A1(1024c)]
  US* t1T  = (US*)alloc(8LL * 256 * 1024 * 2);
  US* h2T  = (US*)alloc(8LL * 256 * 1024 * 2);
  US* g2   = (US*)alloc(8LL * 1024 * 256 * 2);
  // stage-2 region: per batch rows [s2T(512) | z2T(256) | AS2T(512)] x 1024
  US* R2   = (US*)alloc(8LL * 1280 * 1024 * 2);
  US* AS2  = (US*)alloc(8LL * 1024 * 512 * 2);
  US* P2o  = (US*)alloc(8LL * 512 * 768 * 2);     // [xp2(256c) | A2(512c)]
  US* t2T  = (US*)alloc(8LL * 128 * 512 * 2);
  float* h3f = (float*)alloc(8LL * 512 * 128 * 4);
  US* zlb  = (US*)alloc(8LL * 512 * 64 * 2);
  US* t3T  = (US*)alloc(8LL * 256 * 512 * 2);
  US* d0   = (US*)alloc(8LL * 512 * 256 * 2);
  US* t4T  = (US*)alloc(8LL * 256 * 512 * 2);
  US* d2   = (US*)alloc(8LL * 1024 * 256 * 2);
  US* t5T  = (US*)alloc(8LL * 256 * 1024 * 2);
  US* d4   = (US*)alloc(8LL * 2048 * 256 * 2);
  US* t6T  = (US*)alloc(8LL * 64 * 2048 * 2);
  float* pm   = (float*)alloc(8LL * 128 * 2048 * 4);
  float* ps   = (float*)alloc(8LL * 128 * 2048 * 4);
  float* Mf   = (float*)alloc(8LL * 2048 * 4);
  float* Sinv = (float*)alloc(8LL * 2048 * 4);
  US* We1T  = (US*)alloc(256 * 64 * 2);
  US* KpKe1 = (US*)alloc(1280 * 256 * 2);   // [Kpool1^T(1024r) | Kemb1^T(256r)]
  US* We2T  = (US*)alloc(256 * 256 * 2);
  US* KpKe2 = (US*)alloc(768 * 256 * 2);    // [Kpool2^T(512r) | Kemb2^T(256r)]
  US* We3T  = (US*)alloc(128 * 256 * 2);
  US* Wd0T  = (US*)alloc(256 * 64 * 2);
  US* Wd1T  = (US*)alloc(256 * 256 * 2);
  US* Wd2T  = (US*)alloc(256 * 256 * 2);
  US* WdfT  = (US*)alloc(64 * 256 * 2);

  // ---- input conversions ----
  f2b_k<<<dim3(2048 * 2048 / 4 / 256), dim3(256), 0, stream>>>(adj, adjb, 2048 * 2048 / 4);
  trans_k<<<dim3(1, 32, 8), dim3(256), 0, stream>>>(x, xT, 2048, 64, 2048LL * 64,
                                                    64LL * 2048);
  {
    WTab tab;
    int toff = 0, i = 0;
    auto add = [&](const float* s, US* d, int R, int C) {
      tab.e[i++] = WT{s, d, R, C, toff};
      toff += (R / 64) * (C / 64);
    };
    add(We1, We1T, 64, 256);
    add(Kpool1, KpKe1, 256, 1024);
    add(Kemb1, KpKe1 + 1024 * 256, 256, 256);
    add(We2, We2T, 256, 256);
    add(Kpool2, KpKe2, 256, 512);
    add(Kemb2, KpKe2 + 512 * 256, 256, 256);
    add(We3, We3T, 256, 128);
    add(Wd0, Wd0T, 64, 256);
    add(Wd1, Wd1T, 256, 256);
    add(Wd2, Wd2T, 256, 256);
    add(Wdf, WdfT, 256, 64);
    wtrans_k<<<dim3(toff), dim3(256), 0, stream>>>(tab);
  }

  const long long SR1 = 2304LL * 2048, SR2 = 1280LL * 1024;
  US* s1T  = R1;                     // [1024][2048] per batch
  US* B1   = R1 + 1024 * 2048;       // rows [z1T(256) | AS1T(1024)]
  US* AS1T = R1 + 1280 * 2048;
  US* s2T  = R2;                     // [512][1024] per batch
  US* B2   = R2 + 512 * 1024;        // rows [z2T(256) | AS2T(512)]
  US* AS2T = R2 + 768 * 1024;
  US* A1c  = P1o + 256;              // A1 = cols 256.. of P1o, lda=1280
  US* A2c  = P2o + 256;              // A2 = cols 256.. of P2o, lda=768

  // ---------------- encode ----------------
  mm(stream, adjb, xT, nullptr, Y0, nullptr, 2048, 64, 2048, 2048, 0, 64LL * 2048,
     2048LL * 64, 0, 0, 0, 64);
  mm(stream, Y0, We1T, be1, h1T, nullptr, 2048, 256, 64, 64, 2048LL * 64, 0, 0,
     256LL * 2048, 1, 1, 128);
  mm(stream, adjb, h1T, nullptr, g1, nullptr, 2048, 256, 2048, 2048, 0,
     256LL * 2048, 2048LL * 256, 0, 0, 0, 128);
  mm(stream, g1, KpKe1, nullptr, R1, nullptr, 2048, 1280, 256, 256, 2048LL * 256,
     0, 0, SR1, 0, 1, 128);  // rows 0-1023: s1 logits^T, 1024-1279: z1T
  sm_partial_k<8><<<dim3(128, 8), dim3(256), 0, stream>>>(s1T, pm, ps, 1024, 2048, SR1, 128);
  sm_combine_k<<<dim3(8), dim3(256), 0, stream>>>(pm, ps, Mf, Sinv, 2048, 128);
  sm_norm_k<8><<<dim3(128, 8), dim3(256), 0, stream>>>(s1T, Mf, Sinv, 1024, 2048, SR1, 128);
  // AS1 dual: normal [2048][1024] + transposed into AS1T slot
  mm(stream, adjb, s1T, nullptr, AS1, AS1T, 2048, 1024, 2048, 2048, 0, SR1,
     2048LL * 1024, SR1, 0, 3, 128);
  // P1 = s1^T @ [z1 | AS1]  ->  [xp1 | A1]   (M=1024, N=1280, K=2048)
  mm(stream, s1T, B1, nullptr, P1o, nullptr, 1024, 1280, 2048, 2048, SR1, SR1,
     1024LL * 1280, 0, 0, 0, 128);
  mm(stream, P1o, We2T, nullptr, t1T, nullptr, 1024, 256, 256, 1280, 1024LL * 1280,
     0, 0, 256LL * 1024, 0, 1, 128);
  mm(stream, A1c, t1T, be2, h2T, nullptr, 1024, 256, 1024, 1280, 1024LL * 1280,
     256LL * 1024, 0, 256LL * 1024, 1, 1, 128);
  mm(stream, A1c, h2T, nullptr, g2, nullptr, 1024, 256, 1024, 1280, 1024LL * 1280,
     256LL * 1024, 1024LL * 256, 0, 0, 0, 128);
  mm(stream, g2, KpKe2, nullptr, R2, nullptr, 1024, 768, 256, 256, 1024LL * 256,
     0, 0, SR2, 0, 1, 128);  // rows 0-511: s2 logits^T, 512-767: z2T
  sm_partial_k<4><<<dim3(64, 8), dim3(256), 0, stream>>>(s2T, pm, ps, 512, 1024, SR2, 64);
  sm_combine_k<<<dim3(8), dim3(256), 0, stream>>>(pm, ps, Mf, Sinv, 1024, 128);
  sm_norm_k<4><<<dim3(64, 8), dim3(256), 0, stream>>>(s2T, Mf, Sinv, 512, 1024, SR2, 64);
  mm(stream, A1c, s2T, nullptr, AS2, AS2T, 1024, 512, 1024, 1280, 1024LL * 1280,
     SR2, 1024LL * 512, SR2, 0, 3, 128);
  // P2 = s2^T @ [z2 | AS2]  ->  [xp2 | A2]   (M=512, N=768, K=1024)
  mm(stream, s2T, B2, nullptr, P2o, nullptr, 512, 768, 1024, 1024, SR2, SR2,
     512LL * 768, 0, 0, 0, 128);
  mm(stream, P2o, We3T, nullptr, t2T, nullptr, 512, 128, 256, 768, 512LL * 768,
     0, 0, 128LL * 512, 0, 1, 128);
  mm(stream, A2c, t2T, be3, h3f, nullptr, 512, 128, 512, 768, 512LL * 768,
     128LL * 512, 512LL * 128, 0, 0, 2, 128);
  reparam_k<<<dim3(8 * 512 * 64 / 256), dim3(256), 0, stream>>>(h3f, eps, out_mean,
                                                                out_lv, zlb, 8 * 512 * 64);

  // ---------------- decode ----------------
  mm(stream, zlb, Wd0T, nullptr, t3T, nullptr, 512, 256, 64, 64, 512LL * 64, 0, 0,
     256LL * 512, 0, 1, 128);
  mm(stream, A2c, t3T, bd0, d0, nullptr, 512, 256, 512, 768, 512LL * 768,
     256LL * 512, 512LL * 256, 0, 1, 0, 128);
  mm(stream, d0, Wd1T, nullptr, t4T, nullptr, 512, 256, 256, 256, 512LL * 256, 0,
     0, 256LL * 512, 0, 1, 128);
  mm(stream, AS2, t4T, bd1, d2, nullptr, 1024, 256, 512, 512, 1024LL * 512,
     256LL * 512, 1024LL * 256, 0, 1, 0, 128);
  mm(stream, d2, Wd2T, nullptr, t5T, nullptr, 1024, 256, 256, 256, 1024LL * 256, 0,
     0, 256LL * 1024, 0, 1, 128);
  mm(stream, AS1, t5T, bd2, d4, nullptr, 2048, 256, 1024, 1024, 2048LL * 1024,
     256LL * 1024, 2048LL * 256, 0, 1, 0, 128);
  mm(stream, d4, WdfT, nullptr, t6T, nullptr, 2048, 64, 256, 256, 2048LL * 256, 0,
     0, 64LL * 2048, 0, 1, 64);
  mm(stream, adjb, t6T, bdf, out, nullptr, 2048, 64, 2048, 2048, 0, 64LL * 2048,
     2048LL * 64, 0, 2, 2, 64);
}